// Round 1
// baseline (508.263 us; speedup 1.0000x reference)
//
#include <hip/hip_runtime.h>
#include <hip/hip_bf16.h>
#include <math.h>

#define N_NODES 50000
#define N_EDGES 600000
#define E_TOT   (N_EDGES + N_NODES)   // 650000 incl self-loops

// ---------------- graph build ----------------

__global__ void count_deg_kernel(const int* __restrict__ ei, int* __restrict__ cnt) {
    int e = blockIdx.x * 256 + threadIdx.x;
    if (e < N_EDGES) atomicAdd(&cnt[ei[N_EDGES + e]], 1);   // dst occurrences
}

__global__ void dinv_kernel(const int* __restrict__ cnt, float* __restrict__ dinv) {
    int i = blockIdx.x * 256 + threadIdx.x;
    if (i < N_NODES) dinv[i] = rsqrtf((float)(cnt[i] + 1));  // +1 self-loop
}

// scan phase 1: per-block sums of deg (= cnt+1)
__global__ void scan_block_sums(const int* __restrict__ cnt, int* __restrict__ partial) {
    __shared__ int sdata[256];
    int i = blockIdx.x * 256 + threadIdx.x;
    sdata[threadIdx.x] = (i < N_NODES) ? (cnt[i] + 1) : 0;
    __syncthreads();
    for (int s = 128; s > 0; s >>= 1) {
        if (threadIdx.x < s) sdata[threadIdx.x] += sdata[threadIdx.x + s];
        __syncthreads();
    }
    if (threadIdx.x == 0) partial[blockIdx.x] = sdata[0];
}

// scan phase 2: exclusive scan of <=256 partials, single block
__global__ void scan_partials(int* __restrict__ partial, int nb) {
    __shared__ int sh[256];
    if (threadIdx.x < nb) sh[threadIdx.x] = partial[threadIdx.x];
    __syncthreads();
    if (threadIdx.x == 0) {
        int run = 0;
        for (int i = 0; i < nb; i++) { int v = sh[i]; sh[i] = run; run += v; }
    }
    __syncthreads();
    if (threadIdx.x < nb) partial[threadIdx.x] = sh[threadIdx.x];
}

// scan phase 3: per-block exclusive scan + partial offset -> row_ptr
__global__ void scan_final(const int* __restrict__ cnt, const int* __restrict__ partial,
                           int* __restrict__ row_ptr) {
    __shared__ int sdata[256];
    int i = blockIdx.x * 256 + threadIdx.x;
    int v = (i < N_NODES) ? (cnt[i] + 1) : 0;
    sdata[threadIdx.x] = v;
    __syncthreads();
    #pragma unroll
    for (int off = 1; off < 256; off <<= 1) {
        int t = (threadIdx.x >= off) ? sdata[threadIdx.x - off] : 0;
        __syncthreads();
        sdata[threadIdx.x] += t;
        __syncthreads();
    }
    if (i < N_NODES) row_ptr[i] = partial[blockIdx.x] + sdata[threadIdx.x] - v;  // exclusive
    if (blockIdx.x == 0 && threadIdx.x == 0) row_ptr[N_NODES] = E_TOT;
}

__global__ void fill_csr_kernel(const int* __restrict__ ei, const int* __restrict__ row_ptr,
                                int* __restrict__ fill, int* __restrict__ csr_src) {
    int e = blockIdx.x * 256 + threadIdx.x;
    if (e >= E_TOT) return;
    int s, d;
    if (e < N_EDGES) { s = ei[e]; d = ei[N_EDGES + e]; }
    else             { s = d = e - N_EDGES; }                 // self-loop
    int pos = row_ptr[d] + atomicAdd(&fill[d], 1);
    csr_src[pos] = s;
}

// ---------------- aggregation (CSR gather, C=128) ----------------
// out[n] = dinv[n] * sum_e dinv[src_e] * H[src_e]  (+bias, relu optional)

__global__ __launch_bounds__(256) void agg128_kernel(
    const float* __restrict__ H, const float* __restrict__ dinv,
    const int* __restrict__ row_ptr, const int* __restrict__ csr_src,
    const float* __restrict__ bias, float* __restrict__ out, int relu) {
    int n = blockIdx.x * 2 + (threadIdx.x >> 7);
    int c = threadIdx.x & 127;
    if (n >= N_NODES) return;
    float acc = 0.f;
    int p0 = row_ptr[n], p1 = row_ptr[n + 1];
    for (int p = p0; p < p1; ++p) {
        int s = csr_src[p];
        acc += dinv[s] * H[(size_t)s * 128 + c];
    }
    float v = acc * dinv[n];
    if (bias) v += bias[c];
    if (relu) v = fmaxf(v, 0.f);
    out[(size_t)n * 128 + c] = v;
}

// ---------------- tiled f32 GEMM: C[M,N] = A[M,K] @ B[K,N] (+bias, relu) ----------------

template<int K, int N>
__global__ __launch_bounds__(256) void gemm_kernel(
    const float* __restrict__ A, const float* __restrict__ B,
    const float* __restrict__ bias, float* __restrict__ C, int M, int relu) {
    const int TM = 64, TN = 64, TK = 16;
    __shared__ float As[TK][TM + 4];   // +4 keeps rows 16B-aligned, 2-way bank alias is free
    __shared__ float Bs[TK][TN + 4];
    int tid = threadIdx.x;
    int m0 = blockIdx.x * TM;
    int n0 = blockIdx.y * TN;
    int tx = tid & 15;    // N dir
    int ty = tid >> 4;    // M dir
    float acc[4][4] = {};
    for (int k0 = 0; k0 < K; k0 += TK) {
        {   // A tile 64x16, transposed into As[k][m]
            int r = tid >> 2;
            int c = (tid & 3) * 4;
            int gr = m0 + r;
            float4 v = make_float4(0.f, 0.f, 0.f, 0.f);
            if (gr < M) v = *(const float4*)(A + (size_t)gr * K + k0 + c);
            As[c + 0][r] = v.x; As[c + 1][r] = v.y; As[c + 2][r] = v.z; As[c + 3][r] = v.w;
        }
        {   // B tile 16x64
            int r = tid >> 4;
            int c = (tid & 15) * 4;
            float4 v = *(const float4*)(B + (size_t)(k0 + r) * N + n0 + c);
            *(float4*)&Bs[r][c] = v;
        }
        __syncthreads();
        #pragma unroll
        for (int k = 0; k < TK; ++k) {
            float a[4], b[4];
            #pragma unroll
            for (int i = 0; i < 4; ++i) a[i] = As[k][ty * 4 + i];
            #pragma unroll
            for (int j = 0; j < 4; ++j) b[j] = Bs[k][tx * 4 + j];
            #pragma unroll
            for (int i = 0; i < 4; ++i)
                #pragma unroll
                for (int j = 0; j < 4; ++j)
                    acc[i][j] += a[i] * b[j];
        }
        __syncthreads();
    }
    #pragma unroll
    for (int i = 0; i < 4; ++i) {
        int gm = m0 + ty * 4 + i;
        if (gm >= M) continue;
        int gn = n0 + tx * 4;
        float4 v = make_float4(acc[i][0], acc[i][1], acc[i][2], acc[i][3]);
        if (bias) { v.x += bias[gn]; v.y += bias[gn + 1]; v.z += bias[gn + 2]; v.w += bias[gn + 3]; }
        if (relu) { v.x = fmaxf(v.x, 0.f); v.y = fmaxf(v.y, 0.f); v.z = fmaxf(v.z, 0.f); v.w = fmaxf(v.w, 0.f); }
        *(float4*)(C + (size_t)gm * N + gn) = v;
    }
}

// ---------------- layer-3 GEMM: [M,128] @ [128,2], one wave per node ----------------

__global__ __launch_bounds__(256) void gemm3_kernel(
    const float* __restrict__ H, const float* __restrict__ W3, float* __restrict__ T) {
    int wave = threadIdx.x >> 6;
    int lane = threadIdx.x & 63;
    int n = blockIdx.x * 4 + wave;
    if (n >= N_NODES) return;
    const float* h = H + (size_t)n * 128;
    float h0 = h[lane], h1 = h[lane + 64];
    float a0 = h0 * W3[lane * 2 + 0] + h1 * W3[(lane + 64) * 2 + 0];
    float a1 = h0 * W3[lane * 2 + 1] + h1 * W3[(lane + 64) * 2 + 1];
    #pragma unroll
    for (int off = 32; off > 0; off >>= 1) {
        a0 += __shfl_down(a0, off);
        a1 += __shfl_down(a1, off);
    }
    if (lane == 0) { T[n * 2 + 0] = a0; T[n * 2 + 1] = a1; }
}

// ---------------- final aggregation (C=2) + bias + log_softmax ----------------

__global__ void agg2_lsm_kernel(const float* __restrict__ T, const float* __restrict__ dinv,
                                const int* __restrict__ row_ptr, const int* __restrict__ csr_src,
                                const float* __restrict__ b3, float* __restrict__ out) {
    int n = blockIdx.x * 256 + threadIdx.x;
    if (n >= N_NODES) return;
    float a0 = 0.f, a1 = 0.f;
    int p0 = row_ptr[n], p1 = row_ptr[n + 1];
    for (int p = p0; p < p1; ++p) {
        int s = csr_src[p];
        float d = dinv[s];
        float2 t = *(const float2*)(T + (size_t)s * 2);
        a0 += d * t.x;
        a1 += d * t.y;
    }
    float dn = dinv[n];
    float v0 = a0 * dn + b3[0];
    float v1 = a1 * dn + b3[1];
    float m = fmaxf(v0, v1);
    float lse = m + logf(expf(v0 - m) + expf(v1 - m));
    out[n * 2 + 0] = v0 - lse;
    out[n * 2 + 1] = v1 - lse;
}

// ---------------- launch ----------------

extern "C" void kernel_launch(void* const* d_in, const int* in_sizes, int n_in,
                              void* d_out, int out_size, void* d_ws, size_t ws_size,
                              hipStream_t stream) {
    const float* x  = (const float*)d_in[0];
    const float* W1 = (const float*)d_in[1];
    const float* b1 = (const float*)d_in[2];
    const float* W2 = (const float*)d_in[3];
    const float* b2 = (const float*)d_in[4];
    const float* W3 = (const float*)d_in[5];
    const float* b3 = (const float*)d_in[6];
    const int*   ei = (const int*)d_in[7];
    float* out = (float*)d_out;

    char* ws = (char*)d_ws;
    size_t off = 0;
    auto alloc = [&](size_t bytes) -> char* {
        char* p = ws + off;
        off = (off + bytes + 255) & ~(size_t)255;
        return p;
    };
    int*   cnt     = (int*)alloc(N_NODES * 4);
    float* dinv    = (float*)alloc(N_NODES * 4);
    int*   row_ptr = (int*)alloc((N_NODES + 1) * 4);
    int*   fill    = (int*)alloc(N_NODES * 4);
    int*   csr_src = (int*)alloc(E_TOT * 4);
    int*   partial = (int*)alloc(256 * 4);
    float* B0      = (float*)alloc((size_t)N_NODES * 128 * 4);  // agg_x / t2 / t3
    float* B1      = (float*)alloc((size_t)N_NODES * 256 * 4);  // h1 / h2

    hipMemsetAsync(cnt,  0, N_NODES * 4, stream);
    hipMemsetAsync(fill, 0, N_NODES * 4, stream);

    int nb = (N_NODES + 255) / 256;  // 196
    count_deg_kernel<<<(N_EDGES + 255) / 256, 256, 0, stream>>>(ei, cnt);
    dinv_kernel<<<nb, 256, 0, stream>>>(cnt, dinv);
    scan_block_sums<<<nb, 256, 0, stream>>>(cnt, partial);
    scan_partials<<<1, 256, 0, stream>>>(partial, nb);
    scan_final<<<nb, 256, 0, stream>>>(cnt, partial, row_ptr);
    fill_csr_kernel<<<(E_TOT + 255) / 256, 256, 0, stream>>>(ei, row_ptr, fill, csr_src);

    // layer 1: aggregate x (C=128) first, then GEMM +b1 +relu  (A(XW) == (AX)W)
    agg128_kernel<<<(N_NODES + 1) / 2, 256, 0, stream>>>(x, dinv, row_ptr, csr_src, nullptr, B0, 0);
    gemm_kernel<128, 256><<<dim3((N_NODES + 63) / 64, 4), 256, 0, stream>>>(B0, W1, b1, B1, N_NODES, 1);

    // layer 2: GEMM first (256->128), then aggregate +b2 +relu
    gemm_kernel<256, 128><<<dim3((N_NODES + 63) / 64, 2), 256, 0, stream>>>(B1, W2, nullptr, B0, N_NODES, 0);
    agg128_kernel<<<(N_NODES + 1) / 2, 256, 0, stream>>>(B0, dinv, row_ptr, csr_src, b2, B1, 1);

    // layer 3: GEMM (128->2), aggregate + b3 + log_softmax
    gemm3_kernel<<<(N_NODES + 3) / 4, 256, 0, stream>>>(B1, W3, B0);
    agg2_lsm_kernel<<<(N_NODES + 255) / 256, 256, 0, stream>>>(B0, dinv, row_ptr, csr_src, b3, out);
}

// Round 2
// 350.166 us; speedup vs baseline: 1.4515x; 1.4515x over previous
//
#include <hip/hip_runtime.h>
#include <hip/hip_bf16.h>
#include <math.h>

#define N_NODES 50000
#define N_EDGES 600000
#define E_TOT   (N_EDGES + N_NODES)   // 650000 incl self-loops

// ---------------- helpers ----------------

__device__ __forceinline__ unsigned short f2bf(float f) {
    unsigned int u = __float_as_uint(f);
    unsigned int r = (u + 0x7fffu + ((u >> 16) & 1u)) >> 16;   // RNE
    return (unsigned short)r;
}

// ---------------- graph build ----------------

__global__ void count_deg_kernel(const int* __restrict__ ei, int* __restrict__ cnt) {
    int e = blockIdx.x * 256 + threadIdx.x;
    if (e < N_EDGES) atomicAdd(&cnt[ei[N_EDGES + e]], 1);   // dst occurrences
}

__global__ void dinv_kernel(const int* __restrict__ cnt, float* __restrict__ dinv) {
    int i = blockIdx.x * 256 + threadIdx.x;
    if (i < N_NODES) dinv[i] = rsqrtf((float)(cnt[i] + 1));  // +1 self-loop
}

__global__ void scan_block_sums(const int* __restrict__ cnt, int* __restrict__ partial) {
    __shared__ int sdata[256];
    int i = blockIdx.x * 256 + threadIdx.x;
    sdata[threadIdx.x] = (i < N_NODES) ? (cnt[i] + 1) : 0;
    __syncthreads();
    for (int s = 128; s > 0; s >>= 1) {
        if (threadIdx.x < s) sdata[threadIdx.x] += sdata[threadIdx.x + s];
        __syncthreads();
    }
    if (threadIdx.x == 0) partial[blockIdx.x] = sdata[0];
}

__global__ void scan_partials(int* __restrict__ partial, int nb) {
    __shared__ int sh[256];
    if (threadIdx.x < nb) sh[threadIdx.x] = partial[threadIdx.x];
    __syncthreads();
    if (threadIdx.x == 0) {
        int run = 0;
        for (int i = 0; i < nb; i++) { int v = sh[i]; sh[i] = run; run += v; }
    }
    __syncthreads();
    if (threadIdx.x < nb) partial[threadIdx.x] = sh[threadIdx.x];
}

__global__ void scan_final(const int* __restrict__ cnt, const int* __restrict__ partial,
                           int* __restrict__ row_ptr) {
    __shared__ int sdata[256];
    int i = blockIdx.x * 256 + threadIdx.x;
    int v = (i < N_NODES) ? (cnt[i] + 1) : 0;
    sdata[threadIdx.x] = v;
    __syncthreads();
    #pragma unroll
    for (int off = 1; off < 256; off <<= 1) {
        int t = (threadIdx.x >= off) ? sdata[threadIdx.x - off] : 0;
        __syncthreads();
        sdata[threadIdx.x] += t;
        __syncthreads();
    }
    if (i < N_NODES) row_ptr[i] = partial[blockIdx.x] + sdata[threadIdx.x] - v;  // exclusive
    if (blockIdx.x == 0 && threadIdx.x == 0) row_ptr[N_NODES] = E_TOT;
}

__global__ void fill_csr_kernel(const int* __restrict__ ei, const int* __restrict__ row_ptr,
                                int* __restrict__ fill, int* __restrict__ csr_src) {
    int e = blockIdx.x * 256 + threadIdx.x;
    if (e >= E_TOT) return;
    int s, d;
    if (e < N_EDGES) { s = ei[e]; d = ei[N_EDGES + e]; }
    else             { s = d = e - N_EDGES; }                 // self-loop
    int pos = row_ptr[d] + atomicAdd(&fill[d], 1);
    csr_src[pos] = s;
}

// ---------------- f32 -> bf16 cast (vector x4) ----------------

__global__ void cast_bf16_kernel(const float* __restrict__ in, unsigned short* __restrict__ out, int n4) {
    int i = blockIdx.x * 256 + threadIdx.x;
    if (i >= n4) return;
    float4 v = *(const float4*)(in + (size_t)i * 4);
    ushort4 o;
    o.x = f2bf(v.x); o.y = f2bf(v.y); o.z = f2bf(v.z); o.w = f2bf(v.w);
    *(ushort4*)(out + (size_t)i * 4) = o;
}

// ---------------- aggregation (bf16 gather, C=128) ----------------
// One wave per node. 16 lanes per edge (8 bf16 = 16B each); 4 edges in flight.
// out[n] = dinv[n] * sum_e dinv[src_e] * H[src_e]  (+bias, relu optional)

__global__ __launch_bounds__(256) void agg128_bf16_kernel(
    const unsigned short* __restrict__ Hb, const float* __restrict__ dinv,
    const int* __restrict__ row_ptr, const int* __restrict__ csr_src,
    const float* __restrict__ bias, float* __restrict__ out, int relu) {
    int wave = threadIdx.x >> 6;
    int lane = threadIdx.x & 63;
    int n = blockIdx.x * 4 + wave;
    if (n >= N_NODES) return;
    int quarter = lane >> 4;      // edge slot 0..3
    int q = lane & 15;            // channel group: q*8 .. q*8+7
    float acc[8] = {};
    int p0 = row_ptr[n], p1 = row_ptr[n + 1];
    int p = p0 + quarter;
    int s = (p < p1) ? csr_src[p] : -1;
    while (s >= 0) {
        int pn = p + 4;
        int sn = (pn < p1) ? csr_src[pn] : -1;       // prefetch next index
        float d = dinv[s];
        uint4 v = *(const uint4*)(Hb + (size_t)s * 128 + q * 8);
        acc[0] += d * __uint_as_float(v.x << 16);
        acc[1] += d * __uint_as_float(v.x & 0xffff0000u);
        acc[2] += d * __uint_as_float(v.y << 16);
        acc[3] += d * __uint_as_float(v.y & 0xffff0000u);
        acc[4] += d * __uint_as_float(v.z << 16);
        acc[5] += d * __uint_as_float(v.z & 0xffff0000u);
        acc[6] += d * __uint_as_float(v.w << 16);
        acc[7] += d * __uint_as_float(v.w & 0xffff0000u);
        p = pn; s = sn;
    }
    #pragma unroll
    for (int i = 0; i < 8; ++i) {
        acc[i] += __shfl_xor(acc[i], 16);
        acc[i] += __shfl_xor(acc[i], 32);
    }
    if (quarter == 0) {
        float dn = dinv[n];
        float o[8];
        #pragma unroll
        for (int i = 0; i < 8; ++i) {
            float v = acc[i] * dn;
            if (bias) v += bias[q * 8 + i];
            if (relu) v = fmaxf(v, 0.f);
            o[i] = v;
        }
        float* dst = out + (size_t)n * 128 + q * 8;
        *(float4*)(dst)     = make_float4(o[0], o[1], o[2], o[3]);
        *(float4*)(dst + 4) = make_float4(o[4], o[5], o[6], o[7]);
    }
}

// ---------------- tiled f32 GEMM: C[M,N] = A[M,K] @ B[K,N] (+bias, relu) ----------------
// OutT = float (f32 store) or unsigned short (bf16 store)

template<int K, int N, typename OutT>
__global__ __launch_bounds__(256) void gemm_kernel(
    const float* __restrict__ A, const float* __restrict__ B,
    const float* __restrict__ bias, OutT* __restrict__ C, int M, int relu) {
    const int TM = 64, TN = 64, TK = 16;
    __shared__ float As[TK][TM + 4];
    __shared__ float Bs[TK][TN + 4];
    int tid = threadIdx.x;
    int m0 = blockIdx.x * TM;
    int n0 = blockIdx.y * TN;
    int tx = tid & 15;    // N dir
    int ty = tid >> 4;    // M dir
    float acc[4][4] = {};
    for (int k0 = 0; k0 < K; k0 += TK) {
        {
            int r = tid >> 2;
            int c = (tid & 3) * 4;
            int gr = m0 + r;
            float4 v = make_float4(0.f, 0.f, 0.f, 0.f);
            if (gr < M) v = *(const float4*)(A + (size_t)gr * K + k0 + c);
            As[c + 0][r] = v.x; As[c + 1][r] = v.y; As[c + 2][r] = v.z; As[c + 3][r] = v.w;
        }
        {
            int r = tid >> 4;
            int c = (tid & 15) * 4;
            float4 v = *(const float4*)(B + (size_t)(k0 + r) * N + n0 + c);
            *(float4*)&Bs[r][c] = v;
        }
        __syncthreads();
        #pragma unroll
        for (int k = 0; k < TK; ++k) {
            float a[4], b[4];
            #pragma unroll
            for (int i = 0; i < 4; ++i) a[i] = As[k][ty * 4 + i];
            #pragma unroll
            for (int j = 0; j < 4; ++j) b[j] = Bs[k][tx * 4 + j];
            #pragma unroll
            for (int i = 0; i < 4; ++i)
                #pragma unroll
                for (int j = 0; j < 4; ++j)
                    acc[i][j] += a[i] * b[j];
        }
        __syncthreads();
    }
    #pragma unroll
    for (int i = 0; i < 4; ++i) {
        int gm = m0 + ty * 4 + i;
        if (gm >= M) continue;
        int gn = n0 + tx * 4;
        float4 v = make_float4(acc[i][0], acc[i][1], acc[i][2], acc[i][3]);
        if (bias) { v.x += bias[gn]; v.y += bias[gn + 1]; v.z += bias[gn + 2]; v.w += bias[gn + 3]; }
        if (relu) { v.x = fmaxf(v.x, 0.f); v.y = fmaxf(v.y, 0.f); v.z = fmaxf(v.z, 0.f); v.w = fmaxf(v.w, 0.f); }
        if constexpr (sizeof(OutT) == 4) {
            *(float4*)((float*)C + (size_t)gm * N + gn) = v;
        } else {
            ushort4 o;
            o.x = f2bf(v.x); o.y = f2bf(v.y); o.z = f2bf(v.z); o.w = f2bf(v.w);
            *(ushort4*)((unsigned short*)C + (size_t)gm * N + gn) = o;
        }
    }
}

// ---------------- layer-3 GEMM: [M,128] @ [128,2], one wave per node ----------------

__global__ __launch_bounds__(256) void gemm3_kernel(
    const float* __restrict__ H, const float* __restrict__ W3, float* __restrict__ T) {
    int wave = threadIdx.x >> 6;
    int lane = threadIdx.x & 63;
    int n = blockIdx.x * 4 + wave;
    if (n >= N_NODES) return;
    const float* h = H + (size_t)n * 128;
    float h0 = h[lane], h1 = h[lane + 64];
    float a0 = h0 * W3[lane * 2 + 0] + h1 * W3[(lane + 64) * 2 + 0];
    float a1 = h0 * W3[lane * 2 + 1] + h1 * W3[(lane + 64) * 2 + 1];
    #pragma unroll
    for (int off = 32; off > 0; off >>= 1) {
        a0 += __shfl_down(a0, off);
        a1 += __shfl_down(a1, off);
    }
    if (lane == 0) { T[n * 2 + 0] = a0; T[n * 2 + 1] = a1; }
}

// ---------------- final aggregation (C=2) + bias + log_softmax ----------------

__global__ void agg2_lsm_kernel(const float* __restrict__ T, const float* __restrict__ dinv,
                                const int* __restrict__ row_ptr, const int* __restrict__ csr_src,
                                const float* __restrict__ b3, float* __restrict__ out) {
    int n = blockIdx.x * 256 + threadIdx.x;
    if (n >= N_NODES) return;
    float a0 = 0.f, a1 = 0.f;
    int p0 = row_ptr[n], p1 = row_ptr[n + 1];
    int s = csr_src[p0];
    for (int p = p0; p < p1; ++p) {
        int sn = (p + 1 < p1) ? csr_src[p + 1] : 0;   // prefetch
        float d = dinv[s];
        float2 t = *(const float2*)(T + (size_t)s * 2);
        a0 += d * t.x;
        a1 += d * t.y;
        s = sn;
    }
    float dn = dinv[n];
    float v0 = a0 * dn + b3[0];
    float v1 = a1 * dn + b3[1];
    float m = fmaxf(v0, v1);
    float lse = m + logf(expf(v0 - m) + expf(v1 - m));
    out[n * 2 + 0] = v0 - lse;
    out[n * 2 + 1] = v1 - lse;
}

// ---------------- launch ----------------

extern "C" void kernel_launch(void* const* d_in, const int* in_sizes, int n_in,
                              void* d_out, int out_size, void* d_ws, size_t ws_size,
                              hipStream_t stream) {
    const float* x  = (const float*)d_in[0];
    const float* W1 = (const float*)d_in[1];
    const float* b1 = (const float*)d_in[2];
    const float* W2 = (const float*)d_in[3];
    const float* b2 = (const float*)d_in[4];
    const float* W3 = (const float*)d_in[5];
    const float* b3 = (const float*)d_in[6];
    const int*   ei = (const int*)d_in[7];
    float* out = (float*)d_out;

    char* ws = (char*)d_ws;
    size_t off = 0;
    auto alloc = [&](size_t bytes) -> char* {
        char* p = ws + off;
        off = (off + bytes + 255) & ~(size_t)255;
        return p;
    };
    int*   cnt     = (int*)alloc(N_NODES * 4);
    float* dinv    = (float*)alloc(N_NODES * 4);
    int*   row_ptr = (int*)alloc((N_NODES + 1) * 4);
    int*   fill    = (int*)alloc(N_NODES * 4);
    int*   csr_src = (int*)alloc(E_TOT * 4);
    int*   partial = (int*)alloc(256 * 4);
    unsigned short* bfbuf = (unsigned short*)alloc((size_t)N_NODES * 128 * 2); // xb, later t2b
    float* B0      = (float*)alloc((size_t)N_NODES * 128 * 4);  // agg_x, later h2
    float* B1      = (float*)alloc((size_t)N_NODES * 256 * 4);  // h1, later T

    hipMemsetAsync(cnt,  0, N_NODES * 4, stream);
    hipMemsetAsync(fill, 0, N_NODES * 4, stream);

    int nb = (N_NODES + 255) / 256;  // 196
    count_deg_kernel<<<(N_EDGES + 255) / 256, 256, 0, stream>>>(ei, cnt);
    dinv_kernel<<<nb, 256, 0, stream>>>(cnt, dinv);
    scan_block_sums<<<nb, 256, 0, stream>>>(cnt, partial);
    scan_partials<<<1, 256, 0, stream>>>(partial, nb);
    scan_final<<<nb, 256, 0, stream>>>(cnt, partial, row_ptr);
    fill_csr_kernel<<<(E_TOT + 255) / 256, 256, 0, stream>>>(ei, row_ptr, fill, csr_src);

    // layer 1: cast x->bf16, aggregate (C=128), then GEMM +b1 +relu  (A(XW) == (AX)W)
    cast_bf16_kernel<<<(N_NODES * 128 / 4 + 255) / 256, 256, 0, stream>>>(x, bfbuf, N_NODES * 128 / 4);
    agg128_bf16_kernel<<<(N_NODES + 3) / 4, 256, 0, stream>>>(bfbuf, dinv, row_ptr, csr_src, nullptr, B0, 0);
    gemm_kernel<128, 256, float><<<dim3((N_NODES + 63) / 64, 4), 256, 0, stream>>>(B0, W1, b1, B1, N_NODES, 1);

    // layer 2: GEMM first (256->128, bf16 out), then aggregate +b2 +relu
    gemm_kernel<256, 128, unsigned short><<<dim3((N_NODES + 63) / 64, 2), 256, 0, stream>>>(B1, W2, nullptr, bfbuf, N_NODES, 0);
    agg128_bf16_kernel<<<(N_NODES + 3) / 4, 256, 0, stream>>>(bfbuf, dinv, row_ptr, csr_src, b2, B0, 1);

    // layer 3: GEMM (128->2), aggregate + b3 + log_softmax
    gemm3_kernel<<<(N_NODES + 3) / 4, 256, 0, stream>>>(B0, W3, B1);
    agg2_lsm_kernel<<<(N_NODES + 255) / 256, 256, 0, stream>>>(B1, dinv, row_ptr, csr_src, b3, out);
}

// Round 3
// 286.497 us; speedup vs baseline: 1.7741x; 1.2222x over previous
//
#include <hip/hip_runtime.h>
#include <hip/hip_bf16.h>
#include <math.h>

#define N_NODES 50000
#define N_EDGES 600000
#define E_TOT   (N_EDGES + N_NODES)   // 650000 incl self-loops
#define M_PAD   50048                 // 391 * 128

typedef __attribute__((ext_vector_type(8))) short bf16x8;
typedef __attribute__((ext_vector_type(4))) float f32x4;
typedef __attribute__((ext_vector_type(8))) unsigned short u16x8;

// ---------------- helpers ----------------

__device__ __forceinline__ unsigned short f2bf(float f) {
    unsigned int u = __float_as_uint(f);
    unsigned int r = (u + 0x7fffu + ((u >> 16) & 1u)) >> 16;   // RNE
    return (unsigned short)r;
}

// async global->LDS, 16B per lane; lds base must be wave-uniform
#define GLD_LDS16(g, l) __builtin_amdgcn_global_load_lds( \
    (__attribute__((address_space(1))) void*)(void*)(g), \
    (__attribute__((address_space(3))) void*)(l), 16, 0, 0)

// ---------------- graph build ----------------

__global__ void count_deg_kernel(const int* __restrict__ ei, int* __restrict__ cnt) {
    int e = blockIdx.x * 256 + threadIdx.x;
    if (e < N_EDGES) atomicAdd(&cnt[ei[N_EDGES + e]], 1);   // dst occurrences
}

__global__ void dinv_kernel(const int* __restrict__ cnt, float* __restrict__ dinv) {
    int i = blockIdx.x * 256 + threadIdx.x;
    if (i < N_NODES) dinv[i] = rsqrtf((float)(cnt[i] + 1));  // +1 self-loop
}

__global__ void scan_block_sums(const int* __restrict__ cnt, int* __restrict__ partial) {
    __shared__ int sdata[256];
    int i = blockIdx.x * 256 + threadIdx.x;
    sdata[threadIdx.x] = (i < N_NODES) ? (cnt[i] + 1) : 0;
    __syncthreads();
    for (int s = 128; s > 0; s >>= 1) {
        if (threadIdx.x < s) sdata[threadIdx.x] += sdata[threadIdx.x + s];
        __syncthreads();
    }
    if (threadIdx.x == 0) partial[blockIdx.x] = sdata[0];
}

__global__ void scan_partials(int* __restrict__ partial, int nb) {
    __shared__ int sh[256];
    if (threadIdx.x < nb) sh[threadIdx.x] = partial[threadIdx.x];
    __syncthreads();
    if (threadIdx.x == 0) {
        int run = 0;
        for (int i = 0; i < nb; i++) { int v = sh[i]; sh[i] = run; run += v; }
    }
    __syncthreads();
    if (threadIdx.x < nb) partial[threadIdx.x] = sh[threadIdx.x];
}

__global__ void scan_final(const int* __restrict__ cnt, const int* __restrict__ partial,
                           int* __restrict__ row_ptr) {
    __shared__ int sdata[256];
    int i = blockIdx.x * 256 + threadIdx.x;
    int v = (i < N_NODES) ? (cnt[i] + 1) : 0;
    sdata[threadIdx.x] = v;
    __syncthreads();
    #pragma unroll
    for (int off = 1; off < 256; off <<= 1) {
        int t = (threadIdx.x >= off) ? sdata[threadIdx.x - off] : 0;
        __syncthreads();
        sdata[threadIdx.x] += t;
        __syncthreads();
    }
    if (i < N_NODES) row_ptr[i] = partial[blockIdx.x] + sdata[threadIdx.x] - v;  // exclusive
    if (blockIdx.x == 0 && threadIdx.x == 0) row_ptr[N_NODES] = E_TOT;
}

__global__ void fill_csr_kernel(const int* __restrict__ ei, const int* __restrict__ row_ptr,
                                int* __restrict__ fill, int* __restrict__ csr_src) {
    int e = blockIdx.x * 256 + threadIdx.x;
    if (e >= E_TOT) return;
    int s, d;
    if (e < N_EDGES) { s = ei[e]; d = ei[N_EDGES + e]; }
    else             { s = d = e - N_EDGES; }                 // self-loop
    int pos = row_ptr[d] + atomicAdd(&fill[d], 1);
    csr_src[pos] = s;
}

// ---------------- casts ----------------

__global__ void cast_bf16_kernel(const float* __restrict__ in, unsigned short* __restrict__ out, int n4) {
    int i = blockIdx.x * 256 + threadIdx.x;
    if (i >= n4) return;
    float4 v = *(const float4*)(in + (size_t)i * 4);
    ushort4 o;
    o.x = f2bf(v.x); o.y = f2bf(v.y); o.z = f2bf(v.z); o.w = f2bf(v.w);
    *(ushort4*)(out + (size_t)i * 4) = o;
}

// W[K][N] f32 -> Wt[N][K] bf16 (tiny, one-shot)
__global__ void cast_transpose_kernel(const float* __restrict__ W, unsigned short* __restrict__ Wt,
                                      int K, int N) {
    int i = blockIdx.x * 256 + threadIdx.x;
    if (i >= K * N) return;
    int k = i / N, n = i - k * N;
    Wt[(size_t)n * K + k] = f2bf(W[i]);
}

// ---------------- aggregation (bf16 gather, C=128) ----------------
// One wave per node; 16 lanes/edge (16B each); 4 edges in flight; index prefetch.
// out[n] = dinv[n] * sum_e dinv[src_e] * H[src_e]  (+bias, relu optional)

template<typename OutT>
__global__ __launch_bounds__(256) void agg128_bf16_kernel(
    const unsigned short* __restrict__ Hb, const float* __restrict__ dinv,
    const int* __restrict__ row_ptr, const int* __restrict__ csr_src,
    const float* __restrict__ bias, OutT* __restrict__ out, int relu) {
    int wave = threadIdx.x >> 6;
    int lane = threadIdx.x & 63;
    int n = blockIdx.x * 4 + wave;
    if (n >= N_NODES) return;
    int quarter = lane >> 4;      // edge slot 0..3
    int q = lane & 15;            // channel group: q*8 .. q*8+7
    float acc[8] = {};
    int p0 = row_ptr[n], p1 = row_ptr[n + 1];
    int p = p0 + quarter;
    int s = (p < p1) ? csr_src[p] : -1;
    while (s >= 0) {
        int pn = p + 4;
        int sn = (pn < p1) ? csr_src[pn] : -1;       // prefetch next index
        float d = dinv[s];
        uint4 v = *(const uint4*)(Hb + (size_t)s * 128 + q * 8);
        acc[0] += d * __uint_as_float(v.x << 16);
        acc[1] += d * __uint_as_float(v.x & 0xffff0000u);
        acc[2] += d * __uint_as_float(v.y << 16);
        acc[3] += d * __uint_as_float(v.y & 0xffff0000u);
        acc[4] += d * __uint_as_float(v.z << 16);
        acc[5] += d * __uint_as_float(v.z & 0xffff0000u);
        acc[6] += d * __uint_as_float(v.w << 16);
        acc[7] += d * __uint_as_float(v.w & 0xffff0000u);
        p = pn; s = sn;
    }
    #pragma unroll
    for (int i = 0; i < 8; ++i) {
        acc[i] += __shfl_xor(acc[i], 16);
        acc[i] += __shfl_xor(acc[i], 32);
    }
    if (quarter == 0) {
        float dn = dinv[n];
        float o[8];
        #pragma unroll
        for (int i = 0; i < 8; ++i) {
            float v = acc[i] * dn;
            if (bias) v += bias[q * 8 + i];
            if (relu) v = fmaxf(v, 0.f);
            o[i] = v;
        }
        if constexpr (sizeof(OutT) == 2) {
            u16x8 ov;
            #pragma unroll
            for (int i = 0; i < 8; ++i) ov[i] = f2bf(o[i]);
            *(u16x8*)((unsigned short*)out + (size_t)n * 128 + q * 8) = ov;
        } else {
            float* dst = (float*)out + (size_t)n * 128 + q * 8;
            *(float4*)(dst)     = make_float4(o[0], o[1], o[2], o[3]);
            *(float4*)(dst + 4) = make_float4(o[4], o[5], o[6], o[7]);
        }
    }
}

// ---------------- MFMA bf16 GEMM: C[M,N] = A[M,K] @ Wt[N,K]^T (+bias, relu) ----------------
// BM=128 BN=64 BK=32, 256 threads (4 waves), wave -> 32x64 via 2x4 16x16x32 frags.
// LDS layout = XOR-swizzled 16B chunks: chunk(row, c8slot) at row*4 + c8slot,
// storing data column-group c8 = c8slot ^ ((row>>1)&3)  -> staging stays contiguous
// (global_load_lds requirement) AND ds_read_b128 frag reads are 2-way (free).

template<int K, int N, bool RELU, bool HASBIAS>
__global__ __launch_bounds__(256) void gemm_mfma_kernel(
    const unsigned short* __restrict__ A,    // [M_PAD][K] bf16
    const unsigned short* __restrict__ Bt,   // [N][K] bf16
    const float* __restrict__ bias,
    unsigned short* __restrict__ C,          // [M_PAD][N] bf16
    int M) {
    const int BM = 128, BN = 64, BK = 32;
    __shared__ __align__(16) unsigned short As[BM * BK];
    __shared__ __align__(16) unsigned short Bs[BN * BK];
    int tid = threadIdx.x;
    int wave = tid >> 6, lane = tid & 63;
    int m0 = blockIdx.x * BM, n0 = blockIdx.y * BN;
    int mm = lane & 15, kg = lane >> 4;

    f32x4 acc[2][4];
    #pragma unroll
    for (int i = 0; i < 2; ++i)
        #pragma unroll
        for (int j = 0; j < 4; ++j)
            acc[i][j] = (f32x4){0.f, 0.f, 0.f, 0.f};

    // LDS frag offsets (in ushorts)
    int am[2], bn[4];
    #pragma unroll
    for (int i = 0; i < 2; ++i) {
        int m = wave * 32 + i * 16 + mm;
        am[i] = (m * 4 + (kg ^ ((m >> 1) & 3))) * 8;
    }
    #pragma unroll
    for (int j = 0; j < 4; ++j) {
        int n = j * 16 + mm;
        bn[j] = (n * 4 + (kg ^ ((n >> 1) & 3))) * 8;
    }

    for (int k0 = 0; k0 < K; k0 += BK) {
        // stage A: 512 chunks = 2 issues
        #pragma unroll
        for (int iss = 0; iss < 2; ++iss) {
            int ci = iss * 256 + tid;
            int r = ci >> 2, c8s = ci & 3;
            int c8 = c8s ^ ((r >> 1) & 3);
            const unsigned short* g = A + (size_t)(m0 + r) * K + k0 + c8 * 8;
            unsigned short* l = As + (size_t)(iss * 256 + (tid & 192)) * 8;  // wave-uniform base
            GLD_LDS16(g, l);
        }
        // stage B: 256 chunks = 1 issue
        {
            int r = tid >> 2, c8s = tid & 3;
            int c8 = c8s ^ ((r >> 1) & 3);
            const unsigned short* g = Bt + (size_t)(n0 + r) * K + k0 + c8 * 8;
            unsigned short* l = Bs + (size_t)(tid & 192) * 8;
            GLD_LDS16(g, l);
        }
        __syncthreads();   // drains vmcnt (incl. global_load_lds) before barrier
        bf16x8 af[2], bfr[4];
        #pragma unroll
        for (int i = 0; i < 2; ++i) af[i] = *(const bf16x8*)(As + am[i]);
        #pragma unroll
        for (int j = 0; j < 4; ++j) bfr[j] = *(const bf16x8*)(Bs + bn[j]);
        #pragma unroll
        for (int i = 0; i < 2; ++i)
            #pragma unroll
            for (int j = 0; j < 4; ++j)
                acc[i][j] = __builtin_amdgcn_mfma_f32_16x16x32_bf16(af[i], bfr[j], acc[i][j], 0, 0, 0);
        __syncthreads();
    }

    // epilogue: C/D layout col=lane&15, row=(lane>>4)*4+reg (m89-verified)
    int row0 = (lane >> 4) * 4;
    #pragma unroll
    for (int i = 0; i < 2; ++i) {
        #pragma unroll
        for (int r = 0; r < 4; ++r) {
            int gm = m0 + wave * 32 + i * 16 + row0 + r;
            if (gm >= M) continue;
            #pragma unroll
            for (int j = 0; j < 4; ++j) {
                int gn = n0 + j * 16 + mm;
                float v = acc[i][j][r];
                if (HASBIAS) v += bias[gn];
                if (RELU) v = fmaxf(v, 0.f);
                C[(size_t)gm * N + gn] = f2bf(v);
            }
        }
    }
}

// ---------------- layer-3 GEMM: [M,128] @ [128,2], one wave per node ----------------

__global__ __launch_bounds__(256) void gemm3_kernel(
    const float* __restrict__ H, const float* __restrict__ W3, float* __restrict__ T) {
    int wave = threadIdx.x >> 6;
    int lane = threadIdx.x & 63;
    int n = blockIdx.x * 4 + wave;
    if (n >= N_NODES) return;
    const float* h = H + (size_t)n * 128;
    float h0 = h[lane], h1 = h[lane + 64];
    float a0 = h0 * W3[lane * 2 + 0] + h1 * W3[(lane + 64) * 2 + 0];
    float a1 = h0 * W3[lane * 2 + 1] + h1 * W3[(lane + 64) * 2 + 1];
    #pragma unroll
    for (int off = 32; off > 0; off >>= 1) {
        a0 += __shfl_down(a0, off);
        a1 += __shfl_down(a1, off);
    }
    if (lane == 0) { T[n * 2 + 0] = a0; T[n * 2 + 1] = a1; }
}

// ---------------- final aggregation (C=2) + bias + log_softmax ----------------

__global__ void agg2_lsm_kernel(const float* __restrict__ T, const float* __restrict__ dinv,
                                const int* __restrict__ row_ptr, const int* __restrict__ csr_src,
                                const float* __restrict__ b3, float* __restrict__ out) {
    int n = blockIdx.x * 256 + threadIdx.x;
    if (n >= N_NODES) return;
    float a0 = 0.f, a1 = 0.f;
    int p0 = row_ptr[n], p1 = row_ptr[n + 1];
    int s = csr_src[p0];
    for (int p = p0; p < p1; ++p) {
        int sn = (p + 1 < p1) ? csr_src[p + 1] : 0;   // prefetch
        float d = dinv[s];
        float2 t = *(const float2*)(T + (size_t)s * 2);
        a0 += d * t.x;
        a1 += d * t.y;
        s = sn;
    }
    float dn = dinv[n];
    float v0 = a0 * dn + b3[0];
    float v1 = a1 * dn + b3[1];
    float m = fmaxf(v0, v1);
    float lse = m + logf(expf(v0 - m) + expf(v1 - m));
    out[n * 2 + 0] = v0 - lse;
    out[n * 2 + 1] = v1 - lse;
}

// ---------------- launch ----------------

extern "C" void kernel_launch(void* const* d_in, const int* in_sizes, int n_in,
                              void* d_out, int out_size, void* d_ws, size_t ws_size,
                              hipStream_t stream) {
    const float* x  = (const float*)d_in[0];
    const float* W1 = (const float*)d_in[1];
    const float* b1 = (const float*)d_in[2];
    const float* W2 = (const float*)d_in[3];
    const float* b2 = (const float*)d_in[4];
    const float* W3 = (const float*)d_in[5];
    const float* b3 = (const float*)d_in[6];
    const int*   ei = (const int*)d_in[7];
    float* out = (float*)d_out;

    char* ws = (char*)d_ws;
    size_t off = 0;
    auto alloc = [&](size_t bytes) -> char* {
        char* p = ws + off;
        off = (off + bytes + 255) & ~(size_t)255;
        return p;
    };
    int*   cnt     = (int*)alloc(N_NODES * 4);
    float* dinv    = (float*)alloc(N_NODES * 4);
    int*   row_ptr = (int*)alloc((N_NODES + 1) * 4);
    int*   fill    = (int*)alloc(N_NODES * 4);
    int*   csr_src = (int*)alloc(E_TOT * 4);
    int*   partial = (int*)alloc(256 * 4);
    unsigned short* xb     = (unsigned short*)alloc((size_t)N_NODES * 128 * 2);
    unsigned short* W1t    = (unsigned short*)alloc((size_t)256 * 128 * 2);
    unsigned short* W2t    = (unsigned short*)alloc((size_t)128 * 256 * 2);
    unsigned short* aggx_b = (unsigned short*)alloc((size_t)M_PAD * 128 * 2);
    unsigned short* h1b    = (unsigned short*)alloc((size_t)M_PAD * 256 * 2);
    unsigned short* t2b    = (unsigned short*)alloc((size_t)N_NODES * 128 * 2);
    float* h2 = (float*)alloc((size_t)N_NODES * 128 * 4);
    float* T  = (float*)alloc((size_t)N_NODES * 2 * 4);

    hipMemsetAsync(cnt,  0, N_NODES * 4, stream);
    hipMemsetAsync(fill, 0, N_NODES * 4, stream);

    int nb = (N_NODES + 255) / 256;  // 196
    count_deg_kernel<<<(N_EDGES + 255) / 256, 256, 0, stream>>>(ei, cnt);
    dinv_kernel<<<nb, 256, 0, stream>>>(cnt, dinv);
    scan_block_sums<<<nb, 256, 0, stream>>>(cnt, partial);
    scan_partials<<<1, 256, 0, stream>>>(partial, nb);
    scan_final<<<nb, 256, 0, stream>>>(cnt, partial, row_ptr);
    fill_csr_kernel<<<(E_TOT + 255) / 256, 256, 0, stream>>>(ei, row_ptr, fill, csr_src);

    // casts
    cast_bf16_kernel<<<(N_NODES * 128 / 4 + 255) / 256, 256, 0, stream>>>(x, xb, N_NODES * 128 / 4);
    cast_transpose_kernel<<<(128 * 256 + 255) / 256, 256, 0, stream>>>(W1, W1t, 128, 256);
    cast_transpose_kernel<<<(256 * 128 + 255) / 256, 256, 0, stream>>>(W2, W2t, 256, 128);

    // layer 1: aggregate x (C=128, bf16 out), then MFMA GEMM +b1 +relu  (A(XW) == (AX)W)
    agg128_bf16_kernel<unsigned short><<<(N_NODES + 3) / 4, 256, 0, stream>>>(
        xb, dinv, row_ptr, csr_src, nullptr, aggx_b, 0);
    gemm_mfma_kernel<128, 256, true, true><<<dim3(M_PAD / 128, 4), 256, 0, stream>>>(
        aggx_b, W1t, b1, h1b, N_NODES);

    // layer 2: MFMA GEMM (256->128, bf16), then aggregate +b2 +relu (f32 out)
    gemm_mfma_kernel<256, 128, false, false><<<dim3(M_PAD / 128, 2), 256, 0, stream>>>(
        h1b, W2t, nullptr, t2b, N_NODES);
    agg128_bf16_kernel<float><<<(N_NODES + 3) / 4, 256, 0, stream>>>(
        t2b, dinv, row_ptr, csr_src, b2, h2, 1);

    // layer 3: GEMM (128->2), aggregate + b3 + log_softmax
    gemm3_kernel<<<(N_NODES + 3) / 4, 256, 0, stream>>>(h2, W3, T);
    agg2_lsm_kernel<<<(N_NODES + 255) / 256, 256, 0, stream>>>(T, dinv, row_ptr, csr_src, b3, out);
}

// Round 4
// 248.379 us; speedup vs baseline: 2.0463x; 1.1535x over previous
//
#include <hip/hip_runtime.h>
#include <hip/hip_bf16.h>
#include <math.h>

#define N_NODES 50000
#define N_EDGES 600000
#define E_TOT   (N_EDGES + N_NODES)   // 650000 incl self-loops
#define M_PAD   50048                 // 391 * 128
#define CSR_CAP 1000064               // worst-case padded edges (<=1.0M) + slack

typedef __attribute__((ext_vector_type(8))) short bf16x8;
typedef __attribute__((ext_vector_type(4))) float f32x4;
typedef __attribute__((ext_vector_type(8))) unsigned short u16x8;

// ---------------- helpers ----------------

__device__ __forceinline__ unsigned short f2bf(float f) {
    unsigned int u = __float_as_uint(f);
    unsigned int r = (u + 0x7fffu + ((u >> 16) & 1u)) >> 16;   // RNE
    return (unsigned short)r;
}

// async global->LDS, 16B per lane; lds base must be wave-uniform
#define GLD_LDS16(g, l) __builtin_amdgcn_global_load_lds( \
    (__attribute__((address_space(1))) void*)(void*)(g), \
    (__attribute__((address_space(3))) void*)(l), 16, 0, 0)

// ---------------- prep: count degrees + weight cast/transpose ----------------
// region A: count dst occurrences; region B/C: W[K][N] f32 -> Wt[N][K] bf16

__global__ void prep_kernel(const int* __restrict__ ei, int* __restrict__ cnt,
                            const float* __restrict__ W1, const float* __restrict__ W2,
                            unsigned short* __restrict__ W1t, unsigned short* __restrict__ W2t) {
    const int NB_E = (N_EDGES + 255) / 256;   // 2344
    int b = blockIdx.x;
    if (b < NB_E) {
        int e = b * 256 + threadIdx.x;
        if (e < N_EDGES) atomicAdd(&cnt[ei[N_EDGES + e]], 1);
    } else if (b < NB_E + 128) {
        int i = (b - NB_E) * 256 + threadIdx.x;          // W1: 128x256
        int k = i >> 8, n = i & 255;
        W1t[(size_t)n * 128 + k] = f2bf(W1[i]);
    } else {
        int i = (b - NB_E - 128) * 256 + threadIdx.x;    // W2: 256x128
        int k = i >> 7, n = i & 127;
        W2t[(size_t)n * 256 + k] = f2bf(W2[i]);
    }
}

// ---------------- scans over padded degree (pdeg = roundup(cnt+1, 8)) ----------------

__global__ void scanA_kernel(const int* __restrict__ cnt, float* __restrict__ dinv,
                             int* __restrict__ partial) {
    __shared__ int sdata[256];
    int i = blockIdx.x * 256 + threadIdx.x;
    int deg = (i < N_NODES) ? (cnt[i] + 1) : 0;
    if (i < N_NODES) dinv[i] = rsqrtf((float)deg);
    sdata[threadIdx.x] = (deg + 7) & ~7;
    __syncthreads();
    for (int s = 128; s > 0; s >>= 1) {
        if (threadIdx.x < s) sdata[threadIdx.x] += sdata[threadIdx.x + s];
        __syncthreads();
    }
    if (threadIdx.x == 0) partial[blockIdx.x] = sdata[0];
}

__global__ void scanB_kernel(int* __restrict__ partial, int nb, int* __restrict__ row_ptr) {
    __shared__ int sh[256];
    if (threadIdx.x < nb) sh[threadIdx.x] = partial[threadIdx.x];
    __syncthreads();
    if (threadIdx.x == 0) {
        int run = 0;
        for (int i = 0; i < nb; i++) { int v = sh[i]; sh[i] = run; run += v; }
        row_ptr[N_NODES] = run;   // total padded edges
    }
    __syncthreads();
    if (threadIdx.x < nb) partial[threadIdx.x] = sh[threadIdx.x];
}

__global__ void scanC_kernel(const int* __restrict__ cnt, const int* __restrict__ partial,
                             int* __restrict__ row_ptr) {
    __shared__ int sdata[256];
    int i = blockIdx.x * 256 + threadIdx.x;
    int v = (i < N_NODES) ? ((cnt[i] + 8) & ~7) : 0;   // (cnt+1 rounded up to 8)
    sdata[threadIdx.x] = v;
    __syncthreads();
    #pragma unroll
    for (int off = 1; off < 256; off <<= 1) {
        int t = (threadIdx.x >= off) ? sdata[threadIdx.x - off] : 0;
        __syncthreads();
        sdata[threadIdx.x] += t;
        __syncthreads();
    }
    if (i < N_NODES) row_ptr[i] = partial[blockIdx.x] + sdata[threadIdx.x] - v;  // exclusive
}

// ---------------- fill: CSR entries + padding + x prescale-cast + dummy row ----------------

__global__ void fill_kernel(const int* __restrict__ ei, const int* __restrict__ cnt,
                            const int* __restrict__ row_ptr, int* __restrict__ fill,
                            int* __restrict__ csr,
                            const float* __restrict__ x, const float* __restrict__ dinv,
                            unsigned short* __restrict__ xs) {
    const int NB_A = (E_TOT + 255) / 256;       // 2540: real edges + self-loops
    const int NB_B = (N_NODES + 255) / 256;     // 196: per-node padding
    const int NB_C = (N_NODES * 128 / 4 + 255) / 256;  // 6250: x prescale-cast (float4)
    int b = blockIdx.x;
    if (b < NB_A) {
        int e = b * 256 + threadIdx.x;
        if (e >= E_TOT) return;
        int s, d;
        if (e < N_EDGES) { s = ei[e]; d = ei[N_EDGES + e]; }
        else             { s = d = e - N_EDGES; }                 // self-loop
        int pos = row_ptr[d] + atomicAdd(&fill[d], 1);
        csr[pos] = s;
    } else if (b < NB_A + NB_B) {
        int i = (b - NB_A) * 256 + threadIdx.x;
        if (i >= N_NODES) return;
        int start = row_ptr[i] + cnt[i] + 1;
        int end = row_ptr[i + 1];
        for (int j = start; j < end; ++j) csr[j] = N_NODES;       // dummy src
    } else if (b < NB_A + NB_B + NB_C) {
        int i = (b - NB_A - NB_B) * 256 + threadIdx.x;            // float4 index
        if (i >= N_NODES * 32) return;
        float d = dinv[i >> 5];                                    // 32 float4 per row
        float4 v = *(const float4*)(x + (size_t)i * 4);
        ushort4 o;
        o.x = f2bf(v.x * d); o.y = f2bf(v.y * d); o.z = f2bf(v.z * d); o.w = f2bf(v.w * d);
        *(ushort4*)(xs + (size_t)i * 4) = o;
    } else {
        if (threadIdx.x < 16)                                      // zero dummy row of xs
            *(uint4*)(xs + (size_t)N_NODES * 128 + threadIdx.x * 8) = make_uint4(0, 0, 0, 0);
    }
}

// ---------------- aggregation (prescaled bf16 gather, C=128) ----------------
// Wave per node; 16 lanes/edge; padded CSR (mult of 8) -> branchless unroll-2:
// 8 row-loads + 8 index-loads in flight per wave. Sum rows, scale by dinv[n].
// LAYER2: +b2, relu, fuse T = h2 @ W3 (128->2) in-register, store Ts = dinv[n]*T.

template<bool LAYER2>
__global__ __launch_bounds__(256) void agg_kernel(
    const unsigned short* __restrict__ Hs, const float* __restrict__ dinv,
    const int* __restrict__ row_ptr, const int* __restrict__ csr,
    const float* __restrict__ bias, const float* __restrict__ W3,
    unsigned short* __restrict__ outb, float2* __restrict__ Ts) {
    int wave = threadIdx.x >> 6;
    int lane = threadIdx.x & 63;
    int n = blockIdx.x * 4 + wave;
    if (LAYER2 && blockIdx.x == 0 && threadIdx.x == 0) Ts[N_NODES] = make_float2(0.f, 0.f);
    if (n >= N_NODES) return;
    int quarter = lane >> 4;      // edge slot 0..3
    int q = lane & 15;            // channel group: q*8 .. q*8+7
    float acc[8] = {};
    int p0 = row_ptr[n], p1 = row_ptr[n + 1];
    int p = p0 + quarter;
    int s0 = csr[p], s1 = csr[p + 4];
    while (p < p1) {
        int pn = p + 8;
        int s2 = csr[pn], s3 = csr[pn + 4];   // prefetch (slack-safe)
        uint4 v0 = *(const uint4*)(Hs + (size_t)s0 * 128 + q * 8);
        uint4 v1 = *(const uint4*)(Hs + (size_t)s1 * 128 + q * 8);
        acc[0] += __uint_as_float(v0.x << 16);
        acc[1] += __uint_as_float(v0.x & 0xffff0000u);
        acc[2] += __uint_as_float(v0.y << 16);
        acc[3] += __uint_as_float(v0.y & 0xffff0000u);
        acc[4] += __uint_as_float(v0.z << 16);
        acc[5] += __uint_as_float(v0.z & 0xffff0000u);
        acc[6] += __uint_as_float(v0.w << 16);
        acc[7] += __uint_as_float(v0.w & 0xffff0000u);
        acc[0] += __uint_as_float(v1.x << 16);
        acc[1] += __uint_as_float(v1.x & 0xffff0000u);
        acc[2] += __uint_as_float(v1.y << 16);
        acc[3] += __uint_as_float(v1.y & 0xffff0000u);
        acc[4] += __uint_as_float(v1.z << 16);
        acc[5] += __uint_as_float(v1.z & 0xffff0000u);
        acc[6] += __uint_as_float(v1.w << 16);
        acc[7] += __uint_as_float(v1.w & 0xffff0000u);
        p = pn; s0 = s2; s1 = s3;
    }
    #pragma unroll
    for (int i = 0; i < 8; ++i) {
        acc[i] += __shfl_xor(acc[i], 16);
        acc[i] += __shfl_xor(acc[i], 32);   // all lanes now hold full sums
    }
    float dn = dinv[n];
    if (!LAYER2) {
        if (quarter == 0) {
            u16x8 ov;
            #pragma unroll
            for (int i = 0; i < 8; ++i) ov[i] = f2bf(acc[i] * dn);
            *(u16x8*)(outb + (size_t)n * 128 + q * 8) = ov;
        }
    } else {
        float t0 = 0.f, t1 = 0.f;
        #pragma unroll
        for (int i = 0; i < 8; ++i) {
            int c = q * 8 + i;
            float h = fmaxf(acc[i] * dn + bias[c], 0.f);          // h2[n][c]
            float2 w = ((const float2*)W3)[c];
            t0 += h * w.x; t1 += h * w.y;
        }
        #pragma unroll
        for (int off = 1; off < 16; off <<= 1) {
            t0 += __shfl_xor(t0, off);
            t1 += __shfl_xor(t1, off);
        }
        if (lane == 0) Ts[n] = make_float2(t0 * dn, t1 * dn);     // prescale for final agg
    }
}

// ---------------- MFMA bf16 GEMM: C[M,N] = A[M,K] @ Wt[N,K]^T ----------------
// BM=128 BN=64 BK=32, 256 threads (4 waves), wave -> 32x64 via 2x4 16x16x32 frags.
// XOR-swizzled 16B LDS chunks: staging contiguous (global_load_lds wave-uniform base)
// AND ds_read_b128 frag reads 2-way aliased (free per m136).
// SCALEROW: multiply row gm by rowscale[gm], zero-fill pad rows (gm>=M).

template<int K, int N, bool RELU, bool HASBIAS, bool SCALEROW>
__global__ __launch_bounds__(256) void gemm_mfma_kernel(
    const unsigned short* __restrict__ A,    // [M_PAD][K] bf16
    const unsigned short* __restrict__ Bt,   // [N][K] bf16
    const float* __restrict__ bias,
    const float* __restrict__ rowscale,
    unsigned short* __restrict__ C,          // [M_PAD][N] bf16
    int M) {
    const int BM = 128, BN = 64, BK = 32;
    __shared__ __align__(16) unsigned short As[BM * BK];
    __shared__ __align__(16) unsigned short Bs[BN * BK];
    int tid = threadIdx.x;
    int wave = tid >> 6, lane = tid & 63;
    int m0 = blockIdx.x * BM, n0 = blockIdx.y * BN;
    int mm = lane & 15, kg = lane >> 4;

    f32x4 acc[2][4];
    #pragma unroll
    for (int i = 0; i < 2; ++i)
        #pragma unroll
        for (int j = 0; j < 4; ++j)
            acc[i][j] = (f32x4){0.f, 0.f, 0.f, 0.f};

    int am[2], bn[4];
    #pragma unroll
    for (int i = 0; i < 2; ++i) {
        int m = wave * 32 + i * 16 + mm;
        am[i] = (m * 4 + (kg ^ ((m >> 1) & 3))) * 8;
    }
    #pragma unroll
    for (int j = 0; j < 4; ++j) {
        int n = j * 16 + mm;
        bn[j] = (n * 4 + (kg ^ ((n >> 1) & 3))) * 8;
    }

    for (int k0 = 0; k0 < K; k0 += BK) {
        #pragma unroll
        for (int iss = 0; iss < 2; ++iss) {
            int ci = iss * 256 + tid;
            int r = ci >> 2, c8s = ci & 3;
            int c8 = c8s ^ ((r >> 1) & 3);
            const unsigned short* g = A + (size_t)(m0 + r) * K + k0 + c8 * 8;
            unsigned short* l = As + (size_t)(iss * 256 + (tid & 192)) * 8;
            GLD_LDS16(g, l);
        }
        {
            int r = tid >> 2, c8s = tid & 3;
            int c8 = c8s ^ ((r >> 1) & 3);
            const unsigned short* g = Bt + (size_t)(n0 + r) * K + k0 + c8 * 8;
            unsigned short* l = Bs + (size_t)(tid & 192) * 8;
            GLD_LDS16(g, l);
        }
        __syncthreads();
        bf16x8 af[2], bfr[4];
        #pragma unroll
        for (int i = 0; i < 2; ++i) af[i] = *(const bf16x8*)(As + am[i]);
        #pragma unroll
        for (int j = 0; j < 4; ++j) bfr[j] = *(const bf16x8*)(Bs + bn[j]);
        #pragma unroll
        for (int i = 0; i < 2; ++i)
            #pragma unroll
            for (int j = 0; j < 4; ++j)
                acc[i][j] = __builtin_amdgcn_mfma_f32_16x16x32_bf16(af[i], bfr[j], acc[i][j], 0, 0, 0);
        __syncthreads();
    }

    // epilogue: C/D layout col=lane&15, row=(lane>>4)*4+reg (m89-verified)
    int row0 = (lane >> 4) * 4;
    #pragma unroll
    for (int i = 0; i < 2; ++i) {
        #pragma unroll
        for (int r = 0; r < 4; ++r) {
            int gm = m0 + wave * 32 + i * 16 + row0 + r;
            if (SCALEROW) {
                float sc = (gm < M) ? rowscale[gm] : 0.f;
                #pragma unroll
                for (int j = 0; j < 4; ++j) {
                    int gn = n0 + j * 16 + mm;
                    C[(size_t)gm * N + gn] = f2bf(acc[i][j][r] * sc);
                }
            } else {
                if (gm >= M) continue;
                #pragma unroll
                for (int j = 0; j < 4; ++j) {
                    int gn = n0 + j * 16 + mm;
                    float v = acc[i][j][r];
                    if (HASBIAS) v += bias[gn];
                    if (RELU) v = fmaxf(v, 0.f);
                    C[(size_t)gm * N + gn] = f2bf(v);
                }
            }
        }
    }
}

// ---------------- final aggregation (C=2, prescaled) + bias + log_softmax ----------------

__global__ void lsm_kernel(const float2* __restrict__ Ts, const float* __restrict__ dinv,
                           const int* __restrict__ row_ptr, const int* __restrict__ csr,
                           const float* __restrict__ b3, float* __restrict__ out) {
    int n = blockIdx.x * 256 + threadIdx.x;
    if (n >= N_NODES) return;
    float a0 = 0.f, a1 = 0.f;
    int p0 = row_ptr[n], p1 = row_ptr[n + 1];
    int s0 = csr[p0], s1 = csr[p0 + 1];
    for (int p = p0; p < p1; p += 2) {
        int s2 = csr[p + 2], s3 = csr[p + 3];    // prefetch (slack-safe)
        float2 u0 = Ts[s0], u1 = Ts[s1];
        a0 += u0.x + u1.x;
        a1 += u0.y + u1.y;
        s0 = s2; s1 = s3;
    }
    float dn = dinv[n];
    float v0 = a0 * dn + b3[0];
    float v1 = a1 * dn + b3[1];
    float m = fmaxf(v0, v1);
    float lse = m + logf(expf(v0 - m) + expf(v1 - m));
    out[n * 2 + 0] = v0 - lse;
    out[n * 2 + 1] = v1 - lse;
}

// ---------------- launch ----------------

extern "C" void kernel_launch(void* const* d_in, const int* in_sizes, int n_in,
                              void* d_out, int out_size, void* d_ws, size_t ws_size,
                              hipStream_t stream) {
    const float* x  = (const float*)d_in[0];
    const float* W1 = (const float*)d_in[1];
    const float* b1 = (const float*)d_in[2];
    const float* W2 = (const float*)d_in[3];
    const float* b2 = (const float*)d_in[4];
    const float* W3 = (const float*)d_in[5];
    const float* b3 = (const float*)d_in[6];
    const int*   ei = (const int*)d_in[7];
    float* out = (float*)d_out;

    char* ws = (char*)d_ws;
    size_t off = 0;
    auto alloc = [&](size_t bytes) -> char* {
        char* p = ws + off;
        off = (off + bytes + 255) & ~(size_t)255;
        return p;
    };
    int*   cnt     = (int*)alloc(N_NODES * 4);
    float* dinv    = (float*)alloc(N_NODES * 4);
    int*   row_ptr = (int*)alloc((N_NODES + 1) * 4);
    int*   fill    = (int*)alloc(N_NODES * 4);
    int*   csr     = (int*)alloc(CSR_CAP * 4);
    int*   partial = (int*)alloc(256 * 4);
    unsigned short* xs     = (unsigned short*)alloc((size_t)(N_NODES + 1) * 128 * 2);
    unsigned short* W1t    = (unsigned short*)alloc((size_t)256 * 128 * 2);
    unsigned short* W2t    = (unsigned short*)alloc((size_t)128 * 256 * 2);
    unsigned short* aggx_b = (unsigned short*)alloc((size_t)M_PAD * 128 * 2);
    unsigned short* h1b    = (unsigned short*)alloc((size_t)M_PAD * 256 * 2);
    unsigned short* t2b    = (unsigned short*)alloc((size_t)M_PAD * 128 * 2);
    float2* Ts = (float2*)alloc((size_t)(N_NODES + 1) * 8);

    hipMemsetAsync(cnt,  0, N_NODES * 4, stream);
    hipMemsetAsync(fill, 0, N_NODES * 4, stream);

    int nb = (N_NODES + 255) / 256;  // 196
    const int NB_E = (N_EDGES + 255) / 256;
    prep_kernel<<<NB_E + 256, 256, 0, stream>>>(ei, cnt, W1, W2, W1t, W2t);
    scanA_kernel<<<nb, 256, 0, stream>>>(cnt, dinv, partial);
    scanB_kernel<<<1, 256, 0, stream>>>(partial, nb, row_ptr);
    scanC_kernel<<<nb, 256, 0, stream>>>(cnt, partial, row_ptr);
    const int NB_A = (E_TOT + 255) / 256, NB_C = (N_NODES * 32 + 255) / 256;
    fill_kernel<<<NB_A + nb + NB_C + 1, 256, 0, stream>>>(ei, cnt, row_ptr, fill, csr, x, dinv, xs);

    // layer 1: aggregate prescaled x (bf16 out), then MFMA GEMM +b1 +relu
    agg_kernel<false><<<(N_NODES + 3) / 4, 256, 0, stream>>>(
        xs, dinv, row_ptr, csr, nullptr, nullptr, aggx_b, nullptr);
    gemm_mfma_kernel<128, 256, true, true, false><<<dim3(M_PAD / 128, 4), 256, 0, stream>>>(
        aggx_b, W1t, b1, nullptr, h1b, N_NODES);

    // layer 2: MFMA GEMM (256->128, x dinv[row], zero pads), then agg + b2 + relu + W3 dot
    gemm_mfma_kernel<256, 128, false, false, true><<<dim3(M_PAD / 128, 2), 256, 0, stream>>>(
        h1b, W2t, nullptr, dinv, t2b, N_NODES);
    agg_kernel<true><<<(N_NODES + 3) / 4, 256, 0, stream>>>(
        t2b, dinv, row_ptr, csr, b2, W3, nullptr, Ts);

    // layer 3: final aggregation (C=2) + b3 + log_softmax
    lsm_kernel<<<(N_NODES + 255) / 256, 256, 0, stream>>>(Ts, dinv, row_ptr, csr, b3, out);
}

// Round 5
// 240.147 us; speedup vs baseline: 2.1165x; 1.0343x over previous
//
#include <hip/hip_runtime.h>
#include <hip/hip_bf16.h>
#include <math.h>

#define N_NODES 50000
#define N_EDGES 600000
#define E_TOT   (N_EDGES + N_NODES)   // 650000 incl self-loops
#define M_PAD   50048                 // 391 * 128
#define CSR_CAP 1400192               // worst case: 600016 + 49999*16 + slack

typedef __attribute__((ext_vector_type(8))) short bf16x8;
typedef __attribute__((ext_vector_type(4))) float f32x4;
typedef __attribute__((ext_vector_type(8))) unsigned short u16x8;

// ---------------- helpers ----------------

__device__ __forceinline__ unsigned short f2bf(float f) {
    unsigned int u = __float_as_uint(f);
    unsigned int r = (u + 0x7fffu + ((u >> 16) & 1u)) >> 16;   // RNE
    return (unsigned short)r;
}

__device__ __forceinline__ void acc_row(float* acc, uint4 v) {
    acc[0] += __uint_as_float(v.x << 16);
    acc[1] += __uint_as_float(v.x & 0xffff0000u);
    acc[2] += __uint_as_float(v.y << 16);
    acc[3] += __uint_as_float(v.y & 0xffff0000u);
    acc[4] += __uint_as_float(v.z << 16);
    acc[5] += __uint_as_float(v.z & 0xffff0000u);
    acc[6] += __uint_as_float(v.w << 16);
    acc[7] += __uint_as_float(v.w & 0xffff0000u);
}

// async global->LDS, 16B per lane; lds base must be wave-uniform
#define GLD_LDS16(g, l) __builtin_amdgcn_global_load_lds( \
    (__attribute__((address_space(1))) void*)(void*)(g), \
    (__attribute__((address_space(3))) void*)(l), 16, 0, 0)

// ---------------- prep: count degrees + weight cast/transpose ----------------

__global__ void prep_kernel(const int* __restrict__ ei, int* __restrict__ cnt,
                            const float* __restrict__ W1, const float* __restrict__ W2,
                            unsigned short* __restrict__ W1t, unsigned short* __restrict__ W2t) {
    const int NB_E = (N_EDGES + 255) / 256;   // 2344
    int b = blockIdx.x;
    if (b < NB_E) {
        int e = b * 256 + threadIdx.x;
        if (e < N_EDGES) atomicAdd(&cnt[ei[N_EDGES + e]], 1);
    } else if (b < NB_E + 128) {
        int i = (b - NB_E) * 256 + threadIdx.x;          // W1: 128x256
        int k = i >> 8, n = i & 255;
        W1t[(size_t)n * 128 + k] = f2bf(W1[i]);
    } else {
        int i = (b - NB_E - 128) * 256 + threadIdx.x;    // W2: 256x128
        int k = i >> 7, n = i & 127;
        W2t[(size_t)n * 256 + k] = f2bf(W2[i]);
    }
}

// ---------------- single-pass scan (decoupled lookback) ----------------
// pdeg[i] = roundup(cnt[i]+1, 16); row_ptr = exclusive scan; dinv = rsqrt(deg).
// 196 blocks; block b publishes its aggregate (always >0) via device-scope atomic,
// then sums aggregates of blocks 0..b-1 (lower-only wait -> no deadlock).

__global__ __launch_bounds__(256) void scan_kernel(
    const int* __restrict__ cnt, float* __restrict__ dinv,
    int* __restrict__ row_ptr, int* __restrict__ blockSum) {
    __shared__ int sdata[256];
    __shared__ int s_prefix;
    int b = blockIdx.x;
    int tid = threadIdx.x;
    int i = b * 256 + tid;
    int deg = (i < N_NODES) ? (cnt[i] + 1) : 0;
    if (i < N_NODES) dinv[i] = rsqrtf((float)deg);
    int v = (i < N_NODES) ? ((deg + 15) & ~15) : 0;
    sdata[tid] = v;
    __syncthreads();
    #pragma unroll
    for (int off = 1; off < 256; off <<= 1) {
        int t = (tid >= off) ? sdata[tid - off] : 0;
        __syncthreads();
        sdata[tid] += t;
        __syncthreads();
    }
    if (tid == 0) atomicExch(&blockSum[b], sdata[255]);   // publish aggregate (device scope)
    if (tid < 64) {
        int sum = 0;
        for (int j = tid; j < b; j += 64) {
            int vj;
            do { vj = atomicAdd(&blockSum[j], 0); } while (vj == 0);
            sum += vj;
        }
        #pragma unroll
        for (int off = 1; off < 64; off <<= 1) sum += __shfl_xor(sum, off);
        if (tid == 0) s_prefix = sum;
    }
    __syncthreads();
    int prefix = s_prefix;
    if (i < N_NODES) row_ptr[i] = prefix + sdata[tid] - v;      // exclusive
    if (i == N_NODES - 1) row_ptr[N_NODES] = prefix + sdata[tid];  // total
}

// ---------------- fill: CSR (ushort) + padding + x prescale-cast + slack ----------------

__global__ void fill_kernel(const int* __restrict__ ei, const int* __restrict__ cnt,
                            const int* __restrict__ row_ptr, int* __restrict__ fill,
                            unsigned short* __restrict__ csr,
                            const float* __restrict__ x, const float* __restrict__ dinv,
                            unsigned short* __restrict__ xs) {
    const int NB_A = (E_TOT + 255) / 256;       // 2540: real edges + self-loops
    const int NB_B = (N_NODES + 255) / 256;     // 196: per-node padding
    const int NB_C = (N_NODES * 32 + 255) / 256;  // 6250: x prescale-cast (float4)
    int b = blockIdx.x;
    if (b < NB_A) {
        int e = b * 256 + threadIdx.x;
        if (e >= E_TOT) return;
        int s, d;
        if (e < N_EDGES) { s = ei[e]; d = ei[N_EDGES + e]; }
        else             { s = d = e - N_EDGES; }                 // self-loop
        int pos = row_ptr[d] + atomicAdd(&fill[d], 1);
        csr[pos] = (unsigned short)s;
    } else if (b < NB_A + NB_B) {
        int i = (b - NB_A) * 256 + threadIdx.x;
        if (i >= N_NODES) return;
        int start = row_ptr[i] + cnt[i] + 1;
        int end = row_ptr[i + 1];
        for (int j = start; j < end; ++j) csr[j] = (unsigned short)N_NODES;  // dummy src
    } else if (b < NB_A + NB_B + NB_C) {
        int i = (b - NB_A - NB_B) * 256 + threadIdx.x;            // float4 index
        if (i >= N_NODES * 32) return;
        float d = dinv[i >> 5];                                    // 32 float4 per row
        float4 v = *(const float4*)(x + (size_t)i * 4);
        ushort4 o;
        o.x = f2bf(v.x * d); o.y = f2bf(v.y * d); o.z = f2bf(v.z * d); o.w = f2bf(v.w * d);
        *(ushort4*)(xs + (size_t)i * 4) = o;
    } else {
        int t = threadIdx.x;
        if (t < 128) csr[row_ptr[N_NODES] + t] = (unsigned short)N_NODES;  // prefetch slack
        else if (t < 144)                                           // zero dummy row of xs
            *(uint4*)(xs + (size_t)N_NODES * 128 + (t - 128) * 8) = make_uint4(0, 0, 0, 0);
    }
}

// ---------------- aggregation (prescaled bf16 gather, C=128) ----------------
// Wave per node; 16 lanes/edge; CSR padded to mult of 16 -> branchless unroll-4:
// 16 row-loads + 16 index-loads in flight per wave. Sum rows, scale by dinv[n].
// LAYER2: +b2, relu, fuse T = h2 @ W3 (128->2) in-register, store Ts = dinv[n]*T.

template<bool LAYER2>
__global__ __launch_bounds__(256) void agg_kernel(
    const unsigned short* __restrict__ Hs, const float* __restrict__ dinv,
    const int* __restrict__ row_ptr, const unsigned short* __restrict__ csr,
    const float* __restrict__ bias, const float* __restrict__ W3,
    unsigned short* __restrict__ outb, float2* __restrict__ Ts) {
    int wave = threadIdx.x >> 6;
    int lane = threadIdx.x & 63;
    int n = blockIdx.x * 4 + wave;
    if (LAYER2 && blockIdx.x == 0 && threadIdx.x == 0) Ts[N_NODES] = make_float2(0.f, 0.f);
    if (n >= N_NODES) return;
    int quarter = lane >> 4;      // edge slot 0..3
    int q = lane & 15;            // channel group: q*8 .. q*8+7
    float acc[8] = {};
    int p0 = row_ptr[n], p1 = row_ptr[n + 1];
    int p = p0 + quarter;
    int s0 = csr[p], s1 = csr[p + 4], s2 = csr[p + 8], s3 = csr[p + 12];
    while (p < p1) {
        int pn = p + 16;
        int t0 = csr[pn], t1 = csr[pn + 4], t2 = csr[pn + 8], t3 = csr[pn + 12]; // slack-safe
        uint4 v0 = *(const uint4*)(Hs + (size_t)s0 * 128 + q * 8);
        uint4 v1 = *(const uint4*)(Hs + (size_t)s1 * 128 + q * 8);
        uint4 v2 = *(const uint4*)(Hs + (size_t)s2 * 128 + q * 8);
        uint4 v3 = *(const uint4*)(Hs + (size_t)s3 * 128 + q * 8);
        acc_row(acc, v0);
        acc_row(acc, v1);
        acc_row(acc, v2);
        acc_row(acc, v3);
        p = pn; s0 = t0; s1 = t1; s2 = t2; s3 = t3;
    }
    #pragma unroll
    for (int i = 0; i < 8; ++i) {
        acc[i] += __shfl_xor(acc[i], 16);
        acc[i] += __shfl_xor(acc[i], 32);   // all lanes now hold full sums
    }
    float dn = dinv[n];
    if (!LAYER2) {
        if (quarter == 0) {
            u16x8 ov;
            #pragma unroll
            for (int i = 0; i < 8; ++i) ov[i] = f2bf(acc[i] * dn);
            *(u16x8*)(outb + (size_t)n * 128 + q * 8) = ov;
        }
    } else {
        float t0 = 0.f, t1 = 0.f;
        #pragma unroll
        for (int i = 0; i < 8; ++i) {
            int c = q * 8 + i;
            float h = fmaxf(acc[i] * dn + bias[c], 0.f);          // h2[n][c]
            float2 w = ((const float2*)W3)[c];
            t0 += h * w.x; t1 += h * w.y;
        }
        #pragma unroll
        for (int off = 1; off < 16; off <<= 1) {
            t0 += __shfl_xor(t0, off);
            t1 += __shfl_xor(t1, off);
        }
        if (lane == 0) Ts[n] = make_float2(t0 * dn, t1 * dn);     // prescale for final agg
    }
}

// ---------------- MFMA bf16 GEMM: C[M,N] = A[M,K] @ Wt[N,K]^T ----------------
// BM=128 BN=64 BK=32, 256 threads (4 waves), wave -> 32x64 via 2x4 16x16x32 frags.
// XOR-swizzled 16B LDS chunks: staging contiguous (global_load_lds wave-uniform base)
// AND ds_read_b128 frag reads 2-way aliased (free per m136).
// SCALEROW: multiply row gm by rowscale[gm], zero-fill pad rows (gm>=M).

template<int K, int N, bool RELU, bool HASBIAS, bool SCALEROW>
__global__ __launch_bounds__(256) void gemm_mfma_kernel(
    const unsigned short* __restrict__ A,    // [M_PAD][K] bf16
    const unsigned short* __restrict__ Bt,   // [N][K] bf16
    const float* __restrict__ bias,
    const float* __restrict__ rowscale,
    unsigned short* __restrict__ C,          // [M_PAD][N] bf16
    int M) {
    const int BM = 128, BN = 64, BK = 32;
    __shared__ __align__(16) unsigned short As[BM * BK];
    __shared__ __align__(16) unsigned short Bs[BN * BK];
    int tid = threadIdx.x;
    int wave = tid >> 6, lane = tid & 63;
    int m0 = blockIdx.x * BM, n0 = blockIdx.y * BN;
    int mm = lane & 15, kg = lane >> 4;

    f32x4 acc[2][4];
    #pragma unroll
    for (int i = 0; i < 2; ++i)
        #pragma unroll
        for (int j = 0; j < 4; ++j)
            acc[i][j] = (f32x4){0.f, 0.f, 0.f, 0.f};

    int am[2], bn[4];
    #pragma unroll
    for (int i = 0; i < 2; ++i) {
        int m = wave * 32 + i * 16 + mm;
        am[i] = (m * 4 + (kg ^ ((m >> 1) & 3))) * 8;
    }
    #pragma unroll
    for (int j = 0; j < 4; ++j) {
        int n = j * 16 + mm;
        bn[j] = (n * 4 + (kg ^ ((n >> 1) & 3))) * 8;
    }

    for (int k0 = 0; k0 < K; k0 += BK) {
        #pragma unroll
        for (int iss = 0; iss < 2; ++iss) {
            int ci = iss * 256 + tid;
            int r = ci >> 2, c8s = ci & 3;
            int c8 = c8s ^ ((r >> 1) & 3);
            const unsigned short* g = A + (size_t)(m0 + r) * K + k0 + c8 * 8;
            unsigned short* l = As + (size_t)(iss * 256 + (tid & 192)) * 8;
            GLD_LDS16(g, l);
        }
        {
            int r = tid >> 2, c8s = tid & 3;
            int c8 = c8s ^ ((r >> 1) & 3);
            const unsigned short* g = Bt + (size_t)(n0 + r) * K + k0 + c8 * 8;
            unsigned short* l = Bs + (size_t)(tid & 192) * 8;
            GLD_LDS16(g, l);
        }
        __syncthreads();
        bf16x8 af[2], bfr[4];
        #pragma unroll
        for (int i = 0; i < 2; ++i) af[i] = *(const bf16x8*)(As + am[i]);
        #pragma unroll
        for (int j = 0; j < 4; ++j) bfr[j] = *(const bf16x8*)(Bs + bn[j]);
        #pragma unroll
        for (int i = 0; i < 2; ++i)
            #pragma unroll
            for (int j = 0; j < 4; ++j)
                acc[i][j] = __builtin_amdgcn_mfma_f32_16x16x32_bf16(af[i], bfr[j], acc[i][j], 0, 0, 0);
        __syncthreads();
    }

    // epilogue: C/D layout col=lane&15, row=(lane>>4)*4+reg (m89-verified)
    int row0 = (lane >> 4) * 4;
    #pragma unroll
    for (int i = 0; i < 2; ++i) {
        #pragma unroll
        for (int r = 0; r < 4; ++r) {
            int gm = m0 + wave * 32 + i * 16 + row0 + r;
            if (SCALEROW) {
                float sc = (gm < M) ? rowscale[gm] : 0.f;
                #pragma unroll
                for (int j = 0; j < 4; ++j) {
                    int gn = n0 + j * 16 + mm;
                    C[(size_t)gm * N + gn] = f2bf(acc[i][j][r] * sc);
                }
            } else {
                if (gm >= M) continue;
                #pragma unroll
                for (int j = 0; j < 4; ++j) {
                    int gn = n0 + j * 16 + mm;
                    float v = acc[i][j][r];
                    if (HASBIAS) v += bias[gn];
                    if (RELU) v = fmaxf(v, 0.f);
                    C[(size_t)gm * N + gn] = f2bf(v);
                }
            }
        }
    }
}

// ---------------- final aggregation (C=2, prescaled) + bias + log_softmax ----------------

__global__ void lsm_kernel(const float2* __restrict__ Ts, const float* __restrict__ dinv,
                           const int* __restrict__ row_ptr, const unsigned short* __restrict__ csr,
                           const float* __restrict__ b3, float* __restrict__ out) {
    int n = blockIdx.x * 256 + threadIdx.x;
    if (n >= N_NODES) return;
    float a0 = 0.f, a1 = 0.f;
    int p0 = row_ptr[n], p1 = row_ptr[n + 1];
    int s0 = csr[p0], s1 = csr[p0 + 1], s2 = csr[p0 + 2], s3 = csr[p0 + 3];
    for (int p = p0; p < p1; p += 4) {
        int t0 = csr[p + 4], t1 = csr[p + 5], t2 = csr[p + 6], t3 = csr[p + 7]; // slack-safe
        float2 u0 = Ts[s0], u1 = Ts[s1], u2 = Ts[s2], u3 = Ts[s3];
        a0 += (u0.x + u1.x) + (u2.x + u3.x);
        a1 += (u0.y + u1.y) + (u2.y + u3.y);
        s0 = t0; s1 = t1; s2 = t2; s3 = t3;
    }
    float dn = dinv[n];
    float v0 = a0 * dn + b3[0];
    float v1 = a1 * dn + b3[1];
    float m = fmaxf(v0, v1);
    float lse = m + logf(expf(v0 - m) + expf(v1 - m));
    out[n * 2 + 0] = v0 - lse;
    out[n * 2 + 1] = v1 - lse;
}

// ---------------- launch ----------------

extern "C" void kernel_launch(void* const* d_in, const int* in_sizes, int n_in,
                              void* d_out, int out_size, void* d_ws, size_t ws_size,
                              hipStream_t stream) {
    const float* x  = (const float*)d_in[0];
    const float* W1 = (const float*)d_in[1];
    const float* b1 = (const float*)d_in[2];
    const float* W2 = (const float*)d_in[3];
    const float* b2 = (const float*)d_in[4];
    const float* W3 = (const float*)d_in[5];
    const float* b3 = (const float*)d_in[6];
    const int*   ei = (const int*)d_in[7];
    float* out = (float*)d_out;

    char* ws = (char*)d_ws;
    size_t off = 0;
    auto alloc = [&](size_t bytes) -> char* {
        char* p = ws + off;
        off = (off + bytes + 255) & ~(size_t)255;
        return p;
    };
    // cnt, fill, blockSum contiguous -> single memset
    int*   cnt      = (int*)alloc(N_NODES * 4);
    int*   fill     = (int*)alloc(N_NODES * 4);
    int*   blockSum = (int*)alloc(256 * 4);
    char*  zero_end = ws + off;
    float* dinv    = (float*)alloc(N_NODES * 4);
    int*   row_ptr = (int*)alloc((N_NODES + 1) * 4);
    unsigned short* csr = (unsigned short*)alloc(CSR_CAP * 2);
    unsigned short* xs     = (unsigned short*)alloc((size_t)(N_NODES + 1) * 128 * 2);
    unsigned short* W1t    = (unsigned short*)alloc((size_t)256 * 128 * 2);
    unsigned short* W2t    = (unsigned short*)alloc((size_t)128 * 256 * 2);
    unsigned short* aggx_b = (unsigned short*)alloc((size_t)M_PAD * 128 * 2);
    unsigned short* h1b    = (unsigned short*)alloc((size_t)M_PAD * 256 * 2);
    unsigned short* t2b    = (unsigned short*)alloc((size_t)M_PAD * 128 * 2);
    float2* Ts = (float2*)alloc((size_t)(N_NODES + 1) * 8);

    hipMemsetAsync(cnt, 0, (size_t)(zero_end - (char*)cnt), stream);

    int nb = (N_NODES + 255) / 256;  // 196
    const int NB_E = (N_EDGES + 255) / 256;
    prep_kernel<<<NB_E + 256, 256, 0, stream>>>(ei, cnt, W1, W2, W1t, W2t);
    scan_kernel<<<nb, 256, 0, stream>>>(cnt, dinv, row_ptr, blockSum);
    const int NB_A = (E_TOT + 255) / 256, NB_C = (N_NODES * 32 + 255) / 256;
    fill_kernel<<<NB_A + nb + NB_C + 1, 256, 0, stream>>>(ei, cnt, row_ptr, fill, csr, x, dinv, xs);

    // layer 1: aggregate prescaled x (bf16 out), then MFMA GEMM +b1 +relu
    agg_kernel<false><<<(N_NODES + 3) / 4, 256, 0, stream>>>(
        xs, dinv, row_ptr, csr, nullptr, nullptr, aggx_b, nullptr);
    gemm_mfma_kernel<128, 256, true, true, false><<<dim3(M_PAD / 128, 4), 256, 0, stream>>>(
        aggx_b, W1t, b1, nullptr, h1b, N_NODES);

    // layer 2: MFMA GEMM (256->128, x dinv[row], zero pads), then agg + b2 + relu + W3 dot
    gemm_mfma_kernel<256, 128, false, false, true><<<dim3(M_PAD / 128, 2), 256, 0, stream>>>(
        h1b, W2t, nullptr, dinv, t2b, N_NODES);
    agg_kernel<true><<<(N_NODES + 3) / 4, 256, 0, stream>>>(
        t2b, dinv, row_ptr, csr, b2, W3, nullptr, Ts);

    // layer 3: final aggregation (C=2) + b3 + log_softmax
    lsm_kernel<<<(N_NODES + 255) / 256, 256, 0, stream>>>(Ts, dinv, row_ptr, csr, b3, out);
}

// Round 6
// 234.349 us; speedup vs baseline: 2.1688x; 1.0247x over previous
//
#include <hip/hip_runtime.h>
#include <hip/hip_bf16.h>
#include <math.h>

#define N_NODES 50000
#define N_EDGES 600000
#define E_TOT   (N_EDGES + N_NODES)   // 650000 incl self-loops
#define M_PAD   50048                 // 391 * 128
#define CSR_CAP 1400192               // worst case: 600016 + 49999*16 + slack

typedef __attribute__((ext_vector_type(8))) short bf16x8;
typedef __attribute__((ext_vector_type(4))) float f32x4;
typedef __attribute__((ext_vector_type(8))) unsigned short u16x8;

// ---------------- helpers ----------------

__device__ __forceinline__ unsigned short f2bf(float f) {
    unsigned int u = __float_as_uint(f);
    unsigned int r = (u + 0x7fffu + ((u >> 16) & 1u)) >> 16;   // RNE
    return (unsigned short)r;
}

__device__ __forceinline__ void acc_row(float* acc, uint4 v) {
    acc[0] += __uint_as_float(v.x << 16);
    acc[1] += __uint_as_float(v.x & 0xffff0000u);
    acc[2] += __uint_as_float(v.y << 16);
    acc[3] += __uint_as_float(v.y & 0xffff0000u);
    acc[4] += __uint_as_float(v.z << 16);
    acc[5] += __uint_as_float(v.z & 0xffff0000u);
    acc[6] += __uint_as_float(v.w << 16);
    acc[7] += __uint_as_float(v.w & 0xffff0000u);
}

// async global->LDS, 16B per lane; lds base must be wave-uniform
#define GLD_LDS16(g, l) __builtin_amdgcn_global_load_lds( \
    (__attribute__((address_space(1))) void*)(void*)(g), \
    (__attribute__((address_space(3))) void*)(l), 16, 0, 0)

// ---------------- prep: count degrees + weight cast/transpose ----------------

__global__ void prep_kernel(const int* __restrict__ ei, int* __restrict__ cnt,
                            const float* __restrict__ W1, const float* __restrict__ W2,
                            unsigned short* __restrict__ W1t, unsigned short* __restrict__ W2t) {
    const int NB_E = (N_EDGES + 255) / 256;   // 2344
    int b = blockIdx.x;
    if (b < NB_E) {
        int e = b * 256 + threadIdx.x;
        if (e < N_EDGES) atomicAdd(&cnt[ei[N_EDGES + e]], 1);
    } else if (b < NB_E + 128) {
        int i = (b - NB_E) * 256 + threadIdx.x;          // W1: 128x256
        int k = i >> 8, n = i & 255;
        W1t[(size_t)n * 128 + k] = f2bf(W1[i]);
    } else {
        int i = (b - NB_E - 128) * 256 + threadIdx.x;    // W2: 256x128
        int k = i >> 7, n = i & 127;
        W2t[(size_t)n * 256 + k] = f2bf(W2[i]);
    }
}

// ---------------- scan (decoupled lookback) + x prescale-cast ----------------
// Blocks 0..195: pdeg scan -> row_ptr, dinv. Blocks 196..: xs = bf16(dinv*x), dummy row.

__global__ __launch_bounds__(256) void scan_kernel(
    const int* __restrict__ cnt, float* __restrict__ dinv,
    int* __restrict__ row_ptr, int* __restrict__ blockSum,
    const float* __restrict__ x, unsigned short* __restrict__ xs) {
    const int NB_S = (N_NODES + 255) / 256;       // 196
    const int NB_C = (N_NODES * 32 + 255) / 256;  // 6250
    int b = blockIdx.x;
    int tid = threadIdx.x;
    if (b < NB_S) {
        __shared__ int sdata[256];
        __shared__ int s_prefix;
        int i = b * 256 + tid;
        int deg = (i < N_NODES) ? (cnt[i] + 1) : 0;
        if (i < N_NODES) dinv[i] = rsqrtf((float)deg);
        int v = (i < N_NODES) ? ((deg + 15) & ~15) : 0;
        sdata[tid] = v;
        __syncthreads();
        #pragma unroll
        for (int off = 1; off < 256; off <<= 1) {
            int t = (tid >= off) ? sdata[tid - off] : 0;
            __syncthreads();
            sdata[tid] += t;
            __syncthreads();
        }
        if (tid == 0) atomicExch(&blockSum[b], sdata[255]);   // publish (device scope)
        if (tid < 64) {
            int sum = 0;
            for (int j = tid; j < b; j += 64) {
                int vj;
                do { vj = atomicAdd(&blockSum[j], 0); } while (vj == 0);
                sum += vj;
            }
            #pragma unroll
            for (int off = 1; off < 64; off <<= 1) sum += __shfl_xor(sum, off);
            if (tid == 0) s_prefix = sum;
        }
        __syncthreads();
        int prefix = s_prefix;
        if (i < N_NODES) row_ptr[i] = prefix + sdata[tid] - v;         // exclusive
        if (i == N_NODES - 1) row_ptr[N_NODES] = prefix + sdata[tid];  // total
    } else if (b < NB_S + NB_C) {
        int i = (b - NB_S) * 256 + tid;               // float4 index
        if (i >= N_NODES * 32) return;
        float d = rsqrtf((float)(cnt[i >> 5] + 1));   // 32 float4 per row
        float4 v = *(const float4*)(x + (size_t)i * 4);
        ushort4 o;
        o.x = f2bf(v.x * d); o.y = f2bf(v.y * d); o.z = f2bf(v.z * d); o.w = f2bf(v.w * d);
        *(ushort4*)(xs + (size_t)i * 4) = o;
    } else {
        if (tid < 16)                                  // zero dummy row of xs
            *(uint4*)(xs + (size_t)N_NODES * 128 + tid * 8) = make_uint4(0, 0, 0, 0);
    }
}

// ---------------- fill: CSR (ushort) + padding + prefetch slack ----------------

__global__ void fill_kernel(const int* __restrict__ ei, const int* __restrict__ cnt,
                            const int* __restrict__ row_ptr, int* __restrict__ fill,
                            unsigned short* __restrict__ csr) {
    const int NB_A = (E_TOT + 255) / 256;       // 2540: real edges + self-loops
    const int NB_B = (N_NODES + 255) / 256;     // 196: per-node padding
    int b = blockIdx.x;
    if (b < NB_A) {
        int e = b * 256 + threadIdx.x;
        if (e >= E_TOT) return;
        int s, d;
        if (e < N_EDGES) { s = ei[e]; d = ei[N_EDGES + e]; }
        else             { s = d = e - N_EDGES; }                 // self-loop
        int pos = row_ptr[d] + atomicAdd(&fill[d], 1);
        csr[pos] = (unsigned short)s;
    } else if (b < NB_A + NB_B) {
        int i = (b - NB_A) * 256 + threadIdx.x;
        if (i >= N_NODES) return;
        int start = row_ptr[i] + cnt[i] + 1;
        int end = row_ptr[i + 1];
        for (int j = start; j < end; ++j) csr[j] = (unsigned short)N_NODES;  // dummy src
    } else {
        int t = threadIdx.x;
        if (t < 128) csr[row_ptr[N_NODES] + t] = (unsigned short)N_NODES;   // prefetch slack
    }
}

// ---------------- aggregation (prescaled bf16 gather, C=128) ----------------
// Wave per node; 16 lanes/edge; CSR padded to mult of 16; quarter q owns edges
// [q*4 .. q*4+4) of each 16-group -> ushort4 index load + 4 row loads in flight,
// 16 row-loads/wave total. Sum rows, scale by dinv[n].
// LAYER2: +b2, relu, fuse T = h2 @ W3 (128->2) in-register, store Ts = dinv[n]*T.

template<bool LAYER2>
__global__ __launch_bounds__(256) void agg_kernel(
    const unsigned short* __restrict__ Hs, const float* __restrict__ dinv,
    const int* __restrict__ row_ptr, const unsigned short* __restrict__ csr,
    const float* __restrict__ bias, const float* __restrict__ W3,
    unsigned short* __restrict__ outb, float2* __restrict__ Ts) {
    int wave = threadIdx.x >> 6;
    int lane = threadIdx.x & 63;
    int n = blockIdx.x * 4 + wave;
    if (LAYER2 && blockIdx.x == 0 && threadIdx.x == 0) Ts[N_NODES] = make_float2(0.f, 0.f);
    if (n >= N_NODES) return;
    int quarter = lane >> 4;      // edge sub-group 0..3
    int q = lane & 15;            // channel group: q*8 .. q*8+7
    float acc[8] = {};
    int p0 = row_ptr[n], p1 = row_ptr[n + 1];
    int p = p0 + quarter * 4;
    ushort4 s4 = *(const ushort4*)(csr + p);
    while (p < p1) {
        int pn = p + 16;
        ushort4 n4 = *(const ushort4*)(csr + pn);     // slack-safe prefetch
        uint4 v0 = *(const uint4*)(Hs + (size_t)s4.x * 128 + q * 8);
        uint4 v1 = *(const uint4*)(Hs + (size_t)s4.y * 128 + q * 8);
        uint4 v2 = *(const uint4*)(Hs + (size_t)s4.z * 128 + q * 8);
        uint4 v3 = *(const uint4*)(Hs + (size_t)s4.w * 128 + q * 8);
        acc_row(acc, v0);
        acc_row(acc, v1);
        acc_row(acc, v2);
        acc_row(acc, v3);
        p = pn; s4 = n4;
    }
    #pragma unroll
    for (int i = 0; i < 8; ++i) {
        acc[i] += __shfl_xor(acc[i], 16);
        acc[i] += __shfl_xor(acc[i], 32);   // all lanes now hold full sums
    }
    float dn = dinv[n];
    if (!LAYER2) {
        if (quarter == 0) {
            u16x8 ov;
            #pragma unroll
            for (int i = 0; i < 8; ++i) ov[i] = f2bf(acc[i] * dn);
            *(u16x8*)(outb + (size_t)n * 128 + q * 8) = ov;
        }
    } else {
        float t0 = 0.f, t1 = 0.f;
        #pragma unroll
        for (int i = 0; i < 8; ++i) {
            int c = q * 8 + i;
            float h = fmaxf(acc[i] * dn + bias[c], 0.f);          // h2[n][c]
            float2 w = ((const float2*)W3)[c];
            t0 += h * w.x; t1 += h * w.y;
        }
        #pragma unroll
        for (int off = 1; off < 16; off <<= 1) {
            t0 += __shfl_xor(t0, off);
            t1 += __shfl_xor(t1, off);
        }
        if (lane == 0) Ts[n] = make_float2(t0 * dn, t1 * dn);     // prescale for final agg
    }
}

// ---------------- fused MFMA GEMM pair: t2 = diag(dinv) * relu(aggx@W1 + b1) @ W2 ----------------
// One block per 128-row stripe (391 blocks, 256 threads = 4 waves).
// Phase 1: h1[128][256] = relu(aggx@W1+b1) computed in 4 n-tiles of 64, stored
//          bf16 in LDS (XOR-swizzled 16B chunks: slot = c8 ^ (m&15), 32 chunks/row).
// Phase 2: t2[128][128] = rowscale * (h1 @ W2) read from LDS, stored bf16 to global.
// LDS: h1 64K + As 8K + Bs 4K = 76K -> 2 blocks/CU; all 391 blocks in one round.

__global__ __launch_bounds__(256) void gemm12_kernel(
    const unsigned short* __restrict__ A,    // aggx [M_PAD][128] bf16
    const unsigned short* __restrict__ W1t,  // [256][128] bf16
    const unsigned short* __restrict__ W2t,  // [128][256] bf16
    const float* __restrict__ b1,
    const float* __restrict__ rowscale,      // dinv
    unsigned short* __restrict__ C,          // t2 [M_PAD][128] bf16
    int M) {
    __shared__ __align__(16) unsigned short h1buf[128 * 256];  // 64 KB
    __shared__ __align__(16) unsigned short As[128 * 32];      // 8 KB
    __shared__ __align__(16) unsigned short Bs[64 * 32];       // 4 KB
    int tid = threadIdx.x;
    int wave = tid >> 6, lane = tid & 63;
    int m0 = blockIdx.x * 128;
    int mm = lane & 15, kg = lane >> 4;
    int row0 = kg * 4;

    // per-K-step tile frag offsets (BK=32, 4 chunks/row, slot = c8 ^ ((m>>1)&3))
    int am[2];
    #pragma unroll
    for (int i = 0; i < 2; ++i) {
        int m = wave * 32 + i * 16 + mm;
        am[i] = (m * 4 + (kg ^ ((m >> 1) & 3))) * 8;
    }
    int bn[4];
    #pragma unroll
    for (int j = 0; j < 4; ++j) {
        int n = j * 16 + mm;
        bn[j] = (n * 4 + (kg ^ ((n >> 1) & 3))) * 8;
    }
    // h1buf row bases for phase-1 writes (rows = wave*32+i*16+row0+r) and
    // phase-2 reads (rows = wave*32+i*16+mm)
    int h1rd[2];
    #pragma unroll
    for (int i = 0; i < 2; ++i) {
        int m = wave * 32 + i * 16 + mm;
        h1rd[i] = m * 32 * 8;   // + (c8 ^ (m&15))*8
    }

    // ---- phase 1: h1 = relu(aggx@W1 + b1), 4 n-tiles of 64 ----
    #pragma unroll 1
    for (int nt = 0; nt < 4; ++nt) {
        int n0 = nt * 64;
        f32x4 acc[2][4];
        #pragma unroll
        for (int i = 0; i < 2; ++i)
            #pragma unroll
            for (int j = 0; j < 4; ++j)
                acc[i][j] = (f32x4){0.f, 0.f, 0.f, 0.f};
        #pragma unroll 1
        for (int k0 = 0; k0 < 128; k0 += 32) {
            #pragma unroll
            for (int iss = 0; iss < 2; ++iss) {       // As: 512 chunks
                int ci = iss * 256 + tid;
                int r = ci >> 2, c8s = ci & 3;
                int c8 = c8s ^ ((r >> 1) & 3);
                const unsigned short* g = A + (size_t)(m0 + r) * 128 + k0 + c8 * 8;
                unsigned short* l = As + (size_t)(iss * 256 + (tid & 192)) * 8;
                GLD_LDS16(g, l);
            }
            {                                          // Bs: 256 chunks (W1t)
                int r = tid >> 2, c8s = tid & 3;
                int c8 = c8s ^ ((r >> 1) & 3);
                const unsigned short* g = W1t + (size_t)(n0 + r) * 128 + k0 + c8 * 8;
                unsigned short* l = Bs + (size_t)(tid & 192) * 8;
                GLD_LDS16(g, l);
            }
            __syncthreads();
            bf16x8 af[2], bfr[4];
            #pragma unroll
            for (int i = 0; i < 2; ++i) af[i] = *(const bf16x8*)(As + am[i]);
            #pragma unroll
            for (int j = 0; j < 4; ++j) bfr[j] = *(const bf16x8*)(Bs + bn[j]);
            #pragma unroll
            for (int i = 0; i < 2; ++i)
                #pragma unroll
                for (int j = 0; j < 4; ++j)
                    acc[i][j] = __builtin_amdgcn_mfma_f32_16x16x32_bf16(af[i], bfr[j], acc[i][j], 0, 0, 0);
            __syncthreads();
        }
        // epilogue n-tile -> h1buf (bf16). col = n0+j*16+mm, rows = wave*32+i*16+row0+r
        float bj[4];
        #pragma unroll
        for (int j = 0; j < 4; ++j) bj[j] = b1[n0 + j * 16 + mm];
        #pragma unroll
        for (int i = 0; i < 2; ++i) {
            #pragma unroll
            for (int r = 0; r < 4; ++r) {
                int ml = wave * 32 + i * 16 + row0 + r;
                int rb = ml * 32 * 8, rx = ml & 15;
                #pragma unroll
                for (int j = 0; j < 4; ++j) {
                    int c = n0 + j * 16 + mm;
                    int c8 = c >> 3;
                    float v = fmaxf(acc[i][j][r] + bj[j], 0.f);
                    h1buf[rb + ((c8 ^ rx) * 8) + (c & 7)] = f2bf(v);
                }
            }
        }
    }
    __syncthreads();   // h1buf complete before phase-2 reads

    // ---- phase 2: t2 = rowscale * (h1 @ W2), 2 n-halves of 64 ----
    #pragma unroll 1
    for (int nh = 0; nh < 2; ++nh) {
        int n0 = nh * 64;
        f32x4 acc[2][4];
        #pragma unroll
        for (int i = 0; i < 2; ++i)
            #pragma unroll
            for (int j = 0; j < 4; ++j)
                acc[i][j] = (f32x4){0.f, 0.f, 0.f, 0.f};
        #pragma unroll 1
        for (int k0 = 0; k0 < 256; k0 += 32) {
            {                                          // Bs: 256 chunks (W2t)
                int r = tid >> 2, c8s = tid & 3;
                int c8 = c8s ^ ((r >> 1) & 3);
                const unsigned short* g = W2t + (size_t)(n0 + r) * 256 + k0 + c8 * 8;
                unsigned short* l = Bs + (size_t)(tid & 192) * 8;
                GLD_LDS16(g, l);
            }
            __syncthreads();
            bf16x8 af[2], bfr[4];
            #pragma unroll
            for (int i = 0; i < 2; ++i) {
                int m = wave * 32 + i * 16 + mm;
                int c8 = (k0 >> 3) + kg;
                af[i] = *(const bf16x8*)(h1buf + h1rd[i] + ((c8 ^ (m & 15)) * 8));
            }
            #pragma unroll
            for (int j = 0; j < 4; ++j) bfr[j] = *(const bf16x8*)(Bs + bn[j]);
            #pragma unroll
            for (int i = 0; i < 2; ++i)
                #pragma unroll
                for (int j = 0; j < 4; ++j)
                    acc[i][j] = __builtin_amdgcn_mfma_f32_16x16x32_bf16(af[i], bfr[j], acc[i][j], 0, 0, 0);
            __syncthreads();
        }
        // epilogue: scale rows (0 for pads), store bf16 to global
        #pragma unroll
        for (int i = 0; i < 2; ++i) {
            #pragma unroll
            for (int r = 0; r < 4; ++r) {
                int gm = m0 + wave * 32 + i * 16 + row0 + r;
                float sc = (gm < M) ? rowscale[gm] : 0.f;
                #pragma unroll
                for (int j = 0; j < 4; ++j) {
                    int gn = n0 + j * 16 + mm;
                    C[(size_t)gm * 128 + gn] = f2bf(acc[i][j][r] * sc);
                }
            }
        }
    }
}

// ---------------- final aggregation (C=2, prescaled) + bias + log_softmax ----------------

__global__ void lsm_kernel(const float2* __restrict__ Ts, const float* __restrict__ dinv,
                           const int* __restrict__ row_ptr, const unsigned short* __restrict__ csr,
                           const float* __restrict__ b3, float* __restrict__ out) {
    int n = blockIdx.x * 256 + threadIdx.x;
    if (n >= N_NODES) return;
    float a0 = 0.f, a1 = 0.f;
    int p0 = row_ptr[n], p1 = row_ptr[n + 1];
    ushort4 s4 = *(const ushort4*)(csr + p0);
    for (int p = p0; p < p1; p += 4) {
        ushort4 n4 = *(const ushort4*)(csr + p + 4);  // slack-safe prefetch
        float2 u0 = Ts[s4.x], u1 = Ts[s4.y], u2 = Ts[s4.z], u3 = Ts[s4.w];
        a0 += (u0.x + u1.x) + (u2.x + u3.x);
        a1 += (u0.y + u1.y) + (u2.y + u3.y);
        s4 = n4;
    }
    float dn = dinv[n];
    float v0 = a0 * dn + b3[0];
    float v1 = a1 * dn + b3[1];
    float m = fmaxf(v0, v1);
    float lse = m + logf(expf(v0 - m) + expf(v1 - m));
    out[n * 2 + 0] = v0 - lse;
    out[n * 2 + 1] = v1 - lse;
}

// ---------------- launch ----------------

extern "C" void kernel_launch(void* const* d_in, const int* in_sizes, int n_in,
                              void* d_out, int out_size, void* d_ws, size_t ws_size,
                              hipStream_t stream) {
    const float* x  = (const float*)d_in[0];
    const float* W1 = (const float*)d_in[1];
    const float* b1 = (const float*)d_in[2];
    const float* W2 = (const float*)d_in[3];
    const float* b2 = (const float*)d_in[4];
    const float* W3 = (const float*)d_in[5];
    const float* b3 = (const float*)d_in[6];
    const int*   ei = (const int*)d_in[7];
    float* out = (float*)d_out;

    char* ws = (char*)d_ws;
    size_t off = 0;
    auto alloc = [&](size_t bytes) -> char* {
        char* p = ws + off;
        off = (off + bytes + 255) & ~(size_t)255;
        return p;
    };
    // cnt, fill, blockSum contiguous -> single memset
    int*   cnt      = (int*)alloc(N_NODES * 4);
    int*   fill     = (int*)alloc(N_NODES * 4);
    int*   blockSum = (int*)alloc(256 * 4);
    char*  zero_end = ws + off;
    float* dinv    = (float*)alloc(N_NODES * 4);
    int*   row_ptr = (int*)alloc((N_NODES + 1) * 4);
    unsigned short* csr = (unsigned short*)alloc(CSR_CAP * 2);
    unsigned short* xs     = (unsigned short*)alloc((size_t)(N_NODES + 1) * 128 * 2);
    unsigned short* W1t    = (unsigned short*)alloc((size_t)256 * 128 * 2);
    unsigned short* W2t    = (unsigned short*)alloc((size_t)128 * 256 * 2);
    unsigned short* aggx_b = (unsigned short*)alloc((size_t)M_PAD * 128 * 2);
    unsigned short* t2b    = (unsigned short*)alloc((size_t)M_PAD * 128 * 2);
    float2* Ts = (float2*)alloc((size_t)(N_NODES + 1) * 8);

    hipMemsetAsync(cnt, 0, (size_t)(zero_end - (char*)cnt), stream);

    int nb = (N_NODES + 255) / 256;  // 196
    const int NB_E = (N_EDGES + 255) / 256;
    prep_kernel<<<NB_E + 256, 256, 0, stream>>>(ei, cnt, W1, W2, W1t, W2t);
    const int NB_C = (N_NODES * 32 + 255) / 256;
    scan_kernel<<<nb + NB_C + 1, 256, 0, stream>>>(cnt, dinv, row_ptr, blockSum, x, xs);
    const int NB_A = (E_TOT + 255) / 256;
    fill_kernel<<<NB_A + nb + 1, 256, 0, stream>>>(ei, cnt, row_ptr, fill, csr);

    // layer 1 agg: aggregate prescaled x (bf16 out)
    agg_kernel<false><<<(N_NODES + 3) / 4, 256, 0, stream>>>(
        xs, dinv, row_ptr, csr, nullptr, nullptr, aggx_b, nullptr);
    // fused layer1 GEMM + layer2 GEMM (h1 lives in LDS)
    gemm12_kernel<<<M_PAD / 128, 256, 0, stream>>>(
        aggx_b, W1t, W2t, b1, dinv, t2b, N_NODES);
    // layer 2 agg + b2 + relu + W3 dot (Ts prescaled)
    agg_kernel<true><<<(N_NODES + 3) / 4, 256, 0, stream>>>(
        t2b, dinv, row_ptr, csr, b2, W3, nullptr, Ts);

    // layer 3: final aggregation (C=2) + b3 + log_softmax
    lsm_kernel<<<(N_NODES + 255) / 256, 256, 0, stream>>>(Ts, dinv, row_ptr, csr, b3, out);
}